// Round 1
// baseline (1066.138 us; speedup 1.0000x reference)
//
#include <hip/hip_runtime.h>
#include <hip/hip_bf16.h>

// GCN 3-layer: h=x@W ; msg=h[src]*norm ; agg=segsum(msg,dst)+b ; relu (layers 1,2)
// norm: self-loops weight 1, deg at dst, dinv[src]*ew*dinv[dst]
// Plan: build CSR by dst once per call (atomic hist + 1-block scan + cursor fill),
// fp32 GEMM with W fully in LDS, per-node wave aggregation (no atomics in agg).

#define K_IN 128  // all layers have in_features == 128

// ---------- norm / CSR construction ----------

__global__ void init_kernel(float* __restrict__ deg, int* __restrict__ cnt, int n) {
    int i = blockIdx.x * blockDim.x + threadIdx.x;
    if (i < n) { deg[i] = 1.0f; cnt[i] = 0; }  // 1.0 = self-loop weight
}

__global__ void deg_kernel(const int* __restrict__ dst, const float* __restrict__ ew,
                           float* __restrict__ deg, int* __restrict__ cnt, int e) {
    int i = blockIdx.x * blockDim.x + threadIdx.x;
    if (i >= e) return;
    int d = dst[i];
    atomicAdd(&deg[d], ew[i]);
    atomicAdd(&cnt[d], 1);
}

__global__ void dinv_kernel(const float* __restrict__ deg, float* __restrict__ dinv, int n) {
    int i = blockIdx.x * blockDim.x + threadIdx.x;
    if (i < n) dinv[i] = rsqrtf(deg[i]);  // deg >= 1 always (self loop)
}

// single-block exclusive scan of cnt[0..n) -> row_ptr (and cursor copy), row_ptr[n]=total
__global__ __launch_bounds__(1024) void scan_kernel(const int* __restrict__ cnt,
                                                    int* __restrict__ row_ptr,
                                                    int* __restrict__ cursor, int n) {
    __shared__ int sums[1024];
    int t = threadIdx.x;
    int ch = (n + 1023) / 1024;
    int base = t * ch;
    int local = 0;
    for (int j = 0; j < ch; j++) {
        int idx = base + j;
        if (idx < n) local += cnt[idx];
    }
    sums[t] = local;
    __syncthreads();
    // Hillis-Steele inclusive scan
    for (int off = 1; off < 1024; off <<= 1) {
        int v = sums[t];
        int u = (t >= off) ? sums[t - off] : 0;
        __syncthreads();
        sums[t] = v + u;
        __syncthreads();
    }
    int running = (t == 0) ? 0 : sums[t - 1];
    for (int j = 0; j < ch; j++) {
        int idx = base + j;
        if (idx < n) {
            row_ptr[idx] = running;
            cursor[idx]  = running;
            running += cnt[idx];
        }
    }
    if (t == 1023) row_ptr[n] = sums[1023];
}

__global__ void fill_kernel(const int* __restrict__ src, const int* __restrict__ dst,
                            const float* __restrict__ ew, const float* __restrict__ dinv,
                            int* __restrict__ cursor, int* __restrict__ col,
                            float* __restrict__ val, int e) {
    int i = blockIdx.x * blockDim.x + threadIdx.x;
    if (i >= e) return;
    int s = src[i], d = dst[i];
    int pos = atomicAdd(&cursor[d], 1);
    col[pos] = s;
    val[pos] = dinv[s] * ew[i] * dinv[d];
}

// ---------- GEMM: H[n x NOUT] = X[n x 128] @ W[128 x NOUT] ----------
// 64 rows/block, 256 threads, thread = 4 rows x (NOUT/16) cols register tile.
template <int NOUT>
__global__ __launch_bounds__(256) void gemm_kernel(const float* __restrict__ X,
                                                   const float* __restrict__ W,
                                                   float* __restrict__ H, int n) {
    constexpr int CN = NOUT / 16;  // cols per thread: 8 (NOUT=128) or 4 (NOUT=64)
    __shared__ float Xs[64][K_IN + 4];
    __shared__ float Ws[K_IN][NOUT];
    int t = threadIdx.x;
    int row0 = blockIdx.x * 64;

    // stage W (128*NOUT floats) via float4
    for (int i = t; i < K_IN * NOUT / 4; i += 256) {
        int k = (i * 4) / NOUT, c = (i * 4) % NOUT;
        float4 w4 = *(const float4*)(W + k * NOUT + c);
        Ws[k][c] = w4.x; Ws[k][c + 1] = w4.y; Ws[k][c + 2] = w4.z; Ws[k][c + 3] = w4.w;
    }
    // stage X tile (64 x 128) via float4
    for (int i = t; i < 64 * K_IN / 4; i += 256) {
        int r = (i * 4) / K_IN, k = (i * 4) % K_IN;
        int row = row0 + r;
        float4 x4 = make_float4(0.f, 0.f, 0.f, 0.f);
        if (row < n) x4 = *(const float4*)(X + (size_t)row * K_IN + k);
        Xs[r][k] = x4.x; Xs[r][k + 1] = x4.y; Xs[r][k + 2] = x4.z; Xs[r][k + 3] = x4.w;
    }
    __syncthreads();

    int tx = t % 16, ty = t / 16;
    int c0 = tx * CN, r0 = ty * 4;
    float acc[4][CN];
#pragma unroll
    for (int i = 0; i < 4; i++)
#pragma unroll
        for (int j = 0; j < CN; j++) acc[i][j] = 0.f;

    for (int k = 0; k < K_IN; k++) {
        float xv[4];
#pragma unroll
        for (int i = 0; i < 4; i++) xv[i] = Xs[r0 + i][k];
#pragma unroll
        for (int j = 0; j < CN; j++) {
            float wv = Ws[k][c0 + j];
#pragma unroll
            for (int i = 0; i < 4; i++) acc[i][j] += xv[i] * wv;
        }
    }

#pragma unroll
    for (int i = 0; i < 4; i++) {
        int row = row0 + r0 + i;
        if (row < n) {
#pragma unroll
            for (int j = 0; j < CN; j += 4) {
                *(float4*)(H + (size_t)row * NOUT + c0 + j) =
                    make_float4(acc[i][j], acc[i][j + 1], acc[i][j + 2], acc[i][j + 3]);
            }
        }
    }
}

// ---------- aggregation: out[i] = selfw*H[i] + sum_edges val*H[col] + b (opt relu) ----------
// one wave per node; lane-parallel over features (F/64 floats per lane)
template <int F, bool RELU>
__global__ __launch_bounds__(256) void agg_kernel(const float* __restrict__ H,
                                                  const int* __restrict__ row_ptr,
                                                  const int* __restrict__ col,
                                                  const float* __restrict__ val,
                                                  const float* __restrict__ dinv,
                                                  const float* __restrict__ bias,
                                                  float* __restrict__ out, int n) {
    constexpr int VPL = F / 64;  // 2 for F=128, 1 for F=64
    int wid = threadIdx.x >> 6;
    int lane = threadIdx.x & 63;
    int node = blockIdx.x * 4 + wid;
    if (node >= n) return;

    int start = row_ptr[node], end = row_ptr[node + 1];
    float di = dinv[node];
    float sw = di * di;  // self-loop norm = dinv*1*dinv

    float acc[VPL];
    const float* hs = H + (size_t)node * F + lane * VPL;
#pragma unroll
    for (int j = 0; j < VPL; j++) acc[j] = hs[j] * sw;

    for (int p = start; p < end; p++) {
        float w = val[p];
        int c = col[p];
        const float* hr = H + (size_t)c * F + lane * VPL;
#pragma unroll
        for (int j = 0; j < VPL; j++) acc[j] += w * hr[j];
    }

#pragma unroll
    for (int j = 0; j < VPL; j++) {
        float o = acc[j] + bias[lane * VPL + j];
        if (RELU) o = fmaxf(o, 0.f);
        out[(size_t)node * F + lane * VPL + j] = o;
    }
}

// ---------- launch ----------

extern "C" void kernel_launch(void* const* d_in, const int* in_sizes, int n_in,
                              void* d_out, int out_size, void* d_ws, size_t ws_size,
                              hipStream_t stream) {
    const float* x   = (const float*)d_in[0];
    const int*   ei  = (const int*)d_in[1];   // int32 (JAX x64 disabled)
    const float* ew  = (const float*)d_in[2];
    const float* W1  = (const float*)d_in[3];
    const float* b1  = (const float*)d_in[4];
    const float* W2  = (const float*)d_in[5];
    const float* b2  = (const float*)d_in[6];
    const float* W3  = (const float*)d_in[7];
    const float* b3  = (const float*)d_in[8];
    float* out = (float*)d_out;

    const int N = in_sizes[0] / K_IN;
    const int E = in_sizes[2];
    const int* src = ei;
    const int* dst = ei + E;

    // workspace carve-up (256B aligned)
    char* w = (char*)d_ws;
    auto alloc = [&](size_t bytes) {
        void* p = (void*)w;
        w += (bytes + 255) & ~(size_t)255;
        return p;
    };
    float* deg     = (float*)alloc((size_t)N * 4);
    float* dinv    = (float*)alloc((size_t)N * 4);
    int*   cnt     = (int*)alloc((size_t)N * 4);
    int*   row_ptr = (int*)alloc((size_t)(N + 1) * 4);
    int*   cursor  = (int*)alloc((size_t)N * 4);
    int*   col     = (int*)alloc((size_t)E * 4);
    float* val     = (float*)alloc((size_t)E * 4);
    float* bufB    = (float*)alloc((size_t)N * 128 * 4);
    float* bufC    = (float*)alloc((size_t)N * 128 * 4);

    int gN = (N + 255) / 256;
    int gE = (E + 255) / 256;

    init_kernel<<<gN, 256, 0, stream>>>(deg, cnt, N);
    deg_kernel<<<gE, 256, 0, stream>>>(dst, ew, deg, cnt, E);
    dinv_kernel<<<gN, 256, 0, stream>>>(deg, dinv, N);
    scan_kernel<<<1, 1024, 0, stream>>>(cnt, row_ptr, cursor, N);
    fill_kernel<<<gE, 256, 0, stream>>>(src, dst, ew, dinv, cursor, col, val, E);

    int gGemm = (N + 63) / 64;
    int gAgg  = (N + 3) / 4;

    // layer 1: x -> bufB -> bufC (relu)
    gemm_kernel<128><<<gGemm, 256, 0, stream>>>(x, W1, bufB, N);
    agg_kernel<128, true><<<gAgg, 256, 0, stream>>>(bufB, row_ptr, col, val, dinv, b1, bufC, N);
    // layer 2: bufC -> bufB -> bufC (relu)
    gemm_kernel<128><<<gGemm, 256, 0, stream>>>(bufC, W2, bufB, N);
    agg_kernel<128, true><<<gAgg, 256, 0, stream>>>(bufB, row_ptr, col, val, dinv, b2, bufC, N);
    // layer 3: bufC -> bufB(64) -> out (no relu)
    gemm_kernel<64><<<gGemm, 256, 0, stream>>>(bufC, W3, bufB, N);
    agg_kernel<64, false><<<gAgg, 256, 0, stream>>>(bufB, row_ptr, col, val, dinv, b3, out, N);
}

// Round 2
// 838.554 us; speedup vs baseline: 1.2714x; 1.2714x over previous
//
#include <hip/hip_runtime.h>
#include <hip/hip_bf16.h>

// GCN 3-layer. R2: agg edge-loop unrolled x8 (8 outstanding gathers, was
// latency-bound at 1 — VALUBusy 14%, 2.2 TB/s), packed int2 (col,val) CSR
// records (halves fill scatter traffic), GEMM k-step-4 float4 LDS reads.

#define K_IN 128  // all layers have in_features == 128

// ---------- norm / CSR construction ----------

__global__ void init_kernel(float* __restrict__ deg, int* __restrict__ cnt, int n) {
    int i = blockIdx.x * blockDim.x + threadIdx.x;
    if (i < n) { deg[i] = 1.0f; cnt[i] = 0; }  // 1.0 = self-loop weight
}

__global__ void deg_kernel(const int* __restrict__ dst, const float* __restrict__ ew,
                           float* __restrict__ deg, int* __restrict__ cnt, int e) {
    int i = blockIdx.x * blockDim.x + threadIdx.x;
    if (i >= e) return;
    int d = dst[i];
    atomicAdd(&deg[d], ew[i]);
    atomicAdd(&cnt[d], 1);
}

__global__ void dinv_kernel(const float* __restrict__ deg, float* __restrict__ dinv, int n) {
    int i = blockIdx.x * blockDim.x + threadIdx.x;
    if (i < n) dinv[i] = rsqrtf(deg[i]);  // deg >= 1 always (self loop)
}

// single-block exclusive scan of cnt[0..n) -> row_ptr (and cursor copy), row_ptr[n]=total
__global__ __launch_bounds__(1024) void scan_kernel(const int* __restrict__ cnt,
                                                    int* __restrict__ row_ptr,
                                                    int* __restrict__ cursor, int n) {
    __shared__ int sums[1024];
    int t = threadIdx.x;
    int ch = (n + 1023) / 1024;
    int base = t * ch;
    int local = 0;
    for (int j = 0; j < ch; j++) {
        int idx = base + j;
        if (idx < n) local += cnt[idx];
    }
    sums[t] = local;
    __syncthreads();
    for (int off = 1; off < 1024; off <<= 1) {
        int v = sums[t];
        int u = (t >= off) ? sums[t - off] : 0;
        __syncthreads();
        sums[t] = v + u;
        __syncthreads();
    }
    int running = (t == 0) ? 0 : sums[t - 1];
    for (int j = 0; j < ch; j++) {
        int idx = base + j;
        if (idx < n) {
            row_ptr[idx] = running;
            cursor[idx]  = running;
            running += cnt[idx];
        }
    }
    if (t == 1023) row_ptr[n] = sums[1023];
}

__global__ void fill_kernel(const int* __restrict__ src, const int* __restrict__ dst,
                            const float* __restrict__ ew, const float* __restrict__ dinv,
                            int* __restrict__ cursor, int2* __restrict__ ep, int e) {
    int i = blockIdx.x * blockDim.x + threadIdx.x;
    if (i >= e) return;
    int s = src[i], d = dst[i];
    int pos = atomicAdd(&cursor[d], 1);
    float v = dinv[s] * ew[i] * dinv[d];
    ep[pos] = make_int2(s, __float_as_int(v));  // one 8B scatter (was two 4B)
}

// ---------- GEMM: H[n x NOUT] = X[n x 128] @ W[128 x NOUT] ----------
// 64 rows/block, 256 threads; thread = rows {ty+16i} x CN cols; k-step-4
// so Xs reads are ds_read_b128 with 2-way (free) bank aliasing.
template <int NOUT>
__global__ __launch_bounds__(256) void gemm_kernel(const float* __restrict__ X,
                                                   const float* __restrict__ W,
                                                   float* __restrict__ H, int n) {
    constexpr int CN = NOUT / 16;  // 8 (NOUT=128) or 4 (NOUT=64)
    __shared__ float Xs[64][K_IN + 4];
    __shared__ float Ws[K_IN][NOUT];
    int t = threadIdx.x;
    int row0 = blockIdx.x * 64;

    for (int i = t; i < K_IN * NOUT / 4; i += 256) {
        int k = (i * 4) / NOUT, c = (i * 4) % NOUT;
        *(float4*)&Ws[k][c] = *(const float4*)(W + k * NOUT + c);
    }
    for (int i = t; i < 64 * K_IN / 4; i += 256) {
        int r = i / 32, k = (i % 32) * 4;
        int row = row0 + r;
        float4 x4 = make_float4(0.f, 0.f, 0.f, 0.f);
        if (row < n) x4 = *(const float4*)(X + (size_t)row * K_IN + k);
        *(float4*)&Xs[r][k] = x4;
    }
    __syncthreads();

    int tx = t & 15, ty = t >> 4;
    int c0 = tx * CN;
    float acc[4][CN];
#pragma unroll
    for (int i = 0; i < 4; i++)
#pragma unroll
        for (int j = 0; j < CN; j++) acc[i][j] = 0.f;

    for (int k = 0; k < K_IN; k += 4) {
        float4 xv[4];
#pragma unroll
        for (int i = 0; i < 4; i++) xv[i] = *(const float4*)&Xs[ty + 16 * i][k];
#pragma unroll
        for (int kk = 0; kk < 4; kk++) {
            float wv[CN];
#pragma unroll
            for (int j = 0; j < CN; j += 4) {
                float4 w4 = *(const float4*)&Ws[k + kk][c0 + j];
                wv[j] = w4.x; wv[j + 1] = w4.y; wv[j + 2] = w4.z; wv[j + 3] = w4.w;
            }
#pragma unroll
            for (int i = 0; i < 4; i++) {
                float xs = (kk == 0) ? xv[i].x : (kk == 1) ? xv[i].y
                          : (kk == 2) ? xv[i].z : xv[i].w;
#pragma unroll
                for (int j = 0; j < CN; j++) acc[i][j] += xs * wv[j];
            }
        }
    }

#pragma unroll
    for (int i = 0; i < 4; i++) {
        int row = row0 + ty + 16 * i;
        if (row < n) {
#pragma unroll
            for (int j = 0; j < CN; j += 4) {
                *(float4*)(H + (size_t)row * NOUT + c0 + j) =
                    make_float4(acc[i][j], acc[i][j + 1], acc[i][j + 2], acc[i][j + 3]);
            }
        }
    }
}

// ---------- aggregation ----------
// one wave per node; edge loop unrolled x8: batch 8 packed (col,val) loads,
// 8 independent H-row gathers in flight, then FMAs.
template <int F, bool RELU>
__global__ __launch_bounds__(256) void agg_kernel(const float* __restrict__ H,
                                                  const int* __restrict__ row_ptr,
                                                  const int2* __restrict__ ep,
                                                  const float* __restrict__ dinv,
                                                  const float* __restrict__ bias,
                                                  float* __restrict__ out, int n) {
    constexpr int VPL = F / 64;  // 2 for F=128, 1 for F=64
    constexpr int UN = 8;
    int wid = threadIdx.x >> 6;
    int lane = threadIdx.x & 63;
    int node = blockIdx.x * 4 + wid;
    if (node >= n) return;

    int start = row_ptr[node], end = row_ptr[node + 1];
    float di = dinv[node];
    float sw = di * di;

    float acc[VPL];
    const float* hs = H + (size_t)node * F + lane * VPL;
#pragma unroll
    for (int j = 0; j < VPL; j++) acc[j] = hs[j] * sw;

    int p = start;
    for (; p + UN <= end; p += UN) {
        int2 e[UN];
#pragma unroll
        for (int u = 0; u < UN; u++) e[u] = ep[p + u];
        float v[UN][VPL];
#pragma unroll
        for (int u = 0; u < UN; u++) {
            const float* hr = H + (size_t)e[u].x * F + lane * VPL;
#pragma unroll
            for (int j = 0; j < VPL; j++) v[u][j] = hr[j];
        }
#pragma unroll
        for (int u = 0; u < UN; u++) {
            float w = __int_as_float(e[u].y);
#pragma unroll
            for (int j = 0; j < VPL; j++) acc[j] += w * v[u][j];
        }
    }
    for (; p < end; p++) {
        int2 e = ep[p];
        float w = __int_as_float(e.y);
        const float* hr = H + (size_t)e.x * F + lane * VPL;
#pragma unroll
        for (int j = 0; j < VPL; j++) acc[j] += w * hr[j];
    }

#pragma unroll
    for (int j = 0; j < VPL; j++) {
        float o = acc[j] + bias[lane * VPL + j];
        if (RELU) o = fmaxf(o, 0.f);
        out[(size_t)node * F + lane * VPL + j] = o;
    }
}

// ---------- launch ----------

extern "C" void kernel_launch(void* const* d_in, const int* in_sizes, int n_in,
                              void* d_out, int out_size, void* d_ws, size_t ws_size,
                              hipStream_t stream) {
    const float* x   = (const float*)d_in[0];
    const int*   ei  = (const int*)d_in[1];   // int32 (JAX x64 disabled)
    const float* ew  = (const float*)d_in[2];
    const float* W1  = (const float*)d_in[3];
    const float* b1  = (const float*)d_in[4];
    const float* W2  = (const float*)d_in[5];
    const float* b2  = (const float*)d_in[6];
    const float* W3  = (const float*)d_in[7];
    const float* b3  = (const float*)d_in[8];
    float* out = (float*)d_out;

    const int N = in_sizes[0] / K_IN;
    const int E = in_sizes[2];
    const int* src = ei;
    const int* dst = ei + E;

    char* w = (char*)d_ws;
    auto alloc = [&](size_t bytes) {
        void* p = (void*)w;
        w += (bytes + 255) & ~(size_t)255;
        return p;
    };
    float* deg     = (float*)alloc((size_t)N * 4);
    float* dinv    = (float*)alloc((size_t)N * 4);
    int*   cnt     = (int*)alloc((size_t)N * 4);
    int*   row_ptr = (int*)alloc((size_t)(N + 1) * 4);
    int*   cursor  = (int*)alloc((size_t)N * 4);
    int2*  ep      = (int2*)alloc((size_t)E * 8);
    float* bufB    = (float*)alloc((size_t)N * 128 * 4);
    float* bufC    = (float*)alloc((size_t)N * 128 * 4);

    int gN = (N + 255) / 256;
    int gE = (E + 255) / 256;

    init_kernel<<<gN, 256, 0, stream>>>(deg, cnt, N);
    deg_kernel<<<gE, 256, 0, stream>>>(dst, ew, deg, cnt, E);
    dinv_kernel<<<gN, 256, 0, stream>>>(deg, dinv, N);
    scan_kernel<<<1, 1024, 0, stream>>>(cnt, row_ptr, cursor, N);
    fill_kernel<<<gE, 256, 0, stream>>>(src, dst, ew, dinv, cursor, ep, E);

    int gGemm = (N + 63) / 64;
    int gAgg  = (N + 3) / 4;

    gemm_kernel<128><<<gGemm, 256, 0, stream>>>(x, W1, bufB, N);
    agg_kernel<128, true><<<gAgg, 256, 0, stream>>>(bufB, row_ptr, ep, dinv, b1, bufC, N);
    gemm_kernel<128><<<gGemm, 256, 0, stream>>>(bufC, W2, bufB, N);
    agg_kernel<128, true><<<gAgg, 256, 0, stream>>>(bufB, row_ptr, ep, dinv, b2, bufC, N);
    gemm_kernel<64><<<gGemm, 256, 0, stream>>>(bufC, W3, bufB, N);
    agg_kernel<64, false><<<gAgg, 256, 0, stream>>>(bufB, row_ptr, ep, dinv, b3, out, N);
}

// Round 3
// 703.571 us; speedup vs baseline: 1.5153x; 1.1919x over previous
//
#include <hip/hip_runtime.h>
#include <hip/hip_bf16.h>

// GCN 3-layer. R3: CSR build with ONE packed 64-bit atomic per edge
// (cnt in low32, fixed-point ew-sum in high32); atomic's returned old count
// = edge's rank within its dst row -> fill pass is atomic-free
// (pos = row_ptr[dst] + rank). Was: 3 atomics/edge across deg+fill,
// deg_kernel alone 144 us at VALUBusy 0.3% (atomic writeback bound).

#define K_IN 128  // all layers have in_features == 128
#define FIX_SCALE 8388608.0f  // 2^23 fixed point for ew sums (max deg ~75 -> fits)

// ---------- norm / CSR construction ----------

__global__ void init_kernel(unsigned long long* __restrict__ packed, int n) {
    int i = blockIdx.x * blockDim.x + threadIdx.x;
    if (i < n) packed[i] = 0ULL;
}

// one 64-bit atomic per edge; rank[i] = old count at dst (order within row)
__global__ void deg_kernel(const int* __restrict__ dst, const float* __restrict__ ew,
                           unsigned long long* __restrict__ packed,
                           int* __restrict__ rank, int e) {
    int i = blockIdx.x * blockDim.x + threadIdx.x;
    if (i >= e) return;
    int d = dst[i];
    unsigned long long fx = (unsigned long long)(unsigned int)(ew[i] * FIX_SCALE + 0.5f);
    unsigned long long inc = (fx << 32) | 1ULL;
    unsigned long long old = atomicAdd(&packed[d], inc);
    rank[i] = (int)(old & 0xffffffffULL);
}

__global__ void dinv_kernel(const unsigned long long* __restrict__ packed,
                            float* __restrict__ dinv, int n) {
    int i = blockIdx.x * blockDim.x + threadIdx.x;
    if (i >= n) return;
    float deg = 1.0f + (float)(packed[i] >> 32) * (1.0f / FIX_SCALE);  // +1 self loop
    dinv[i] = rsqrtf(deg);
}

// single-block exclusive scan of counts -> row_ptr, row_ptr[n]=total
__global__ __launch_bounds__(1024) void scan_kernel(const unsigned long long* __restrict__ packed,
                                                    int* __restrict__ row_ptr, int n) {
    __shared__ int sums[1024];
    int t = threadIdx.x;
    int ch = (n + 1023) / 1024;
    int base = t * ch;
    int local = 0;
    for (int j = 0; j < ch; j++) {
        int idx = base + j;
        if (idx < n) local += (int)(packed[idx] & 0xffffffffULL);
    }
    sums[t] = local;
    __syncthreads();
    for (int off = 1; off < 1024; off <<= 1) {
        int v = sums[t];
        int u = (t >= off) ? sums[t - off] : 0;
        __syncthreads();
        sums[t] = v + u;
        __syncthreads();
    }
    int running = (t == 0) ? 0 : sums[t - 1];
    for (int j = 0; j < ch; j++) {
        int idx = base + j;
        if (idx < n) {
            row_ptr[idx] = running;
            running += (int)(packed[idx] & 0xffffffffULL);
        }
    }
    if (t == 1023) row_ptr[n] = sums[1023];
}

// atomic-free fill: pos = row_ptr[dst] + rank
__global__ void fill_kernel(const int* __restrict__ src, const int* __restrict__ dst,
                            const float* __restrict__ ew, const float* __restrict__ dinv,
                            const int* __restrict__ row_ptr, const int* __restrict__ rank,
                            int2* __restrict__ ep, int e) {
    int i = blockIdx.x * blockDim.x + threadIdx.x;
    if (i >= e) return;
    int s = src[i], d = dst[i];
    int pos = row_ptr[d] + rank[i];
    float v = dinv[s] * ew[i] * dinv[d];
    ep[pos] = make_int2(s, __float_as_int(v));
}

// ---------- GEMM: H[n x NOUT] = X[n x 128] @ W[128 x NOUT] ----------
template <int NOUT>
__global__ __launch_bounds__(256) void gemm_kernel(const float* __restrict__ X,
                                                   const float* __restrict__ W,
                                                   float* __restrict__ H, int n) {
    constexpr int CN = NOUT / 16;  // 8 (NOUT=128) or 4 (NOUT=64)
    __shared__ float Xs[64][K_IN + 4];
    __shared__ float Ws[K_IN][NOUT];
    int t = threadIdx.x;
    int row0 = blockIdx.x * 64;

    for (int i = t; i < K_IN * NOUT / 4; i += 256) {
        int k = (i * 4) / NOUT, c = (i * 4) % NOUT;
        *(float4*)&Ws[k][c] = *(const float4*)(W + k * NOUT + c);
    }
    for (int i = t; i < 64 * K_IN / 4; i += 256) {
        int r = i / 32, k = (i % 32) * 4;
        int row = row0 + r;
        float4 x4 = make_float4(0.f, 0.f, 0.f, 0.f);
        if (row < n) x4 = *(const float4*)(X + (size_t)row * K_IN + k);
        *(float4*)&Xs[r][k] = x4;
    }
    __syncthreads();

    int tx = t & 15, ty = t >> 4;
    int c0 = tx * CN;
    float acc[4][CN];
#pragma unroll
    for (int i = 0; i < 4; i++)
#pragma unroll
        for (int j = 0; j < CN; j++) acc[i][j] = 0.f;

    for (int k = 0; k < K_IN; k += 4) {
        float4 xv[4];
#pragma unroll
        for (int i = 0; i < 4; i++) xv[i] = *(const float4*)&Xs[ty + 16 * i][k];
#pragma unroll
        for (int kk = 0; kk < 4; kk++) {
            float wv[CN];
#pragma unroll
            for (int j = 0; j < CN; j += 4) {
                float4 w4 = *(const float4*)&Ws[k + kk][c0 + j];
                wv[j] = w4.x; wv[j + 1] = w4.y; wv[j + 2] = w4.z; wv[j + 3] = w4.w;
            }
#pragma unroll
            for (int i = 0; i < 4; i++) {
                float xs = (kk == 0) ? xv[i].x : (kk == 1) ? xv[i].y
                          : (kk == 2) ? xv[i].z : xv[i].w;
#pragma unroll
                for (int j = 0; j < CN; j++) acc[i][j] += xs * wv[j];
            }
        }
    }

#pragma unroll
    for (int i = 0; i < 4; i++) {
        int row = row0 + ty + 16 * i;
        if (row < n) {
#pragma unroll
            for (int j = 0; j < CN; j += 4) {
                *(float4*)(H + (size_t)row * NOUT + c0 + j) =
                    make_float4(acc[i][j], acc[i][j + 1], acc[i][j + 2], acc[i][j + 3]);
            }
        }
    }
}

// ---------- aggregation ----------
// one wave per node; edge loop unrolled x8 (8 gathers in flight)
template <int F, bool RELU>
__global__ __launch_bounds__(256) void agg_kernel(const float* __restrict__ H,
                                                  const int* __restrict__ row_ptr,
                                                  const int2* __restrict__ ep,
                                                  const float* __restrict__ dinv,
                                                  const float* __restrict__ bias,
                                                  float* __restrict__ out, int n) {
    constexpr int VPL = F / 64;  // 2 for F=128, 1 for F=64
    constexpr int UN = 8;
    int wid = threadIdx.x >> 6;
    int lane = threadIdx.x & 63;
    int node = blockIdx.x * 4 + wid;
    if (node >= n) return;

    int start = row_ptr[node], end = row_ptr[node + 1];
    float di = dinv[node];
    float sw = di * di;

    float acc[VPL];
    const float* hs = H + (size_t)node * F + lane * VPL;
#pragma unroll
    for (int j = 0; j < VPL; j++) acc[j] = hs[j] * sw;

    int p = start;
    for (; p + UN <= end; p += UN) {
        int2 e[UN];
#pragma unroll
        for (int u = 0; u < UN; u++) e[u] = ep[p + u];
        float v[UN][VPL];
#pragma unroll
        for (int u = 0; u < UN; u++) {
            const float* hr = H + (size_t)e[u].x * F + lane * VPL;
#pragma unroll
            for (int j = 0; j < VPL; j++) v[u][j] = hr[j];
        }
#pragma unroll
        for (int u = 0; u < UN; u++) {
            float w = __int_as_float(e[u].y);
#pragma unroll
            for (int j = 0; j < VPL; j++) acc[j] += w * v[u][j];
        }
    }
    for (; p < end; p++) {
        int2 e = ep[p];
        float w = __int_as_float(e.y);
        const float* hr = H + (size_t)e.x * F + lane * VPL;
#pragma unroll
        for (int j = 0; j < VPL; j++) acc[j] += w * hr[j];
    }

#pragma unroll
    for (int j = 0; j < VPL; j++) {
        float o = acc[j] + bias[lane * VPL + j];
        if (RELU) o = fmaxf(o, 0.f);
        out[(size_t)node * F + lane * VPL + j] = o;
    }
}

// ---------- launch ----------

extern "C" void kernel_launch(void* const* d_in, const int* in_sizes, int n_in,
                              void* d_out, int out_size, void* d_ws, size_t ws_size,
                              hipStream_t stream) {
    const float* x   = (const float*)d_in[0];
    const int*   ei  = (const int*)d_in[1];   // int32 (JAX x64 disabled)
    const float* ew  = (const float*)d_in[2];
    const float* W1  = (const float*)d_in[3];
    const float* b1  = (const float*)d_in[4];
    const float* W2  = (const float*)d_in[5];
    const float* b2  = (const float*)d_in[6];
    const float* W3  = (const float*)d_in[7];
    const float* b3  = (const float*)d_in[8];
    float* out = (float*)d_out;

    const int N = in_sizes[0] / K_IN;
    const int E = in_sizes[2];
    const int* src = ei;
    const int* dst = ei + E;

    char* w = (char*)d_ws;
    auto alloc = [&](size_t bytes) {
        void* p = (void*)w;
        w += (bytes + 255) & ~(size_t)255;
        return p;
    };
    unsigned long long* packed = (unsigned long long*)alloc((size_t)N * 8);
    float* dinv    = (float*)alloc((size_t)N * 4);
    int*   row_ptr = (int*)alloc((size_t)(N + 1) * 4);
    int*   rank    = (int*)alloc((size_t)E * 4);
    int2*  ep      = (int2*)alloc((size_t)E * 8);
    float* bufB    = (float*)alloc((size_t)N * 128 * 4);
    float* bufC    = (float*)alloc((size_t)N * 128 * 4);

    int gN = (N + 255) / 256;
    int gE = (E + 255) / 256;

    init_kernel<<<gN, 256, 0, stream>>>(packed, N);
    deg_kernel<<<gE, 256, 0, stream>>>(dst, ew, packed, rank, E);
    dinv_kernel<<<gN, 256, 0, stream>>>(packed, dinv, N);
    scan_kernel<<<1, 1024, 0, stream>>>(packed, row_ptr, N);
    fill_kernel<<<gE, 256, 0, stream>>>(src, dst, ew, dinv, row_ptr, rank, ep, E);

    int gGemm = (N + 63) / 64;
    int gAgg  = (N + 3) / 4;

    gemm_kernel<128><<<gGemm, 256, 0, stream>>>(x, W1, bufB, N);
    agg_kernel<128, true><<<gAgg, 256, 0, stream>>>(bufB, row_ptr, ep, dinv, b1, bufC, N);
    gemm_kernel<128><<<gGemm, 256, 0, stream>>>(bufC, W2, bufB, N);
    agg_kernel<128, true><<<gAgg, 256, 0, stream>>>(bufB, row_ptr, ep, dinv, b2, bufC, N);
    gemm_kernel<64><<<gGemm, 256, 0, stream>>>(bufC, W3, bufB, N);
    agg_kernel<64, false><<<gAgg, 256, 0, stream>>>(bufB, row_ptr, ep, dinv, b3, out, N);
}

// Round 4
// 591.502 us; speedup vs baseline: 1.8024x; 1.1895x over previous
//
#include <hip/hip_runtime.h>
#include <hip/hip_bf16.h>

// GCN 3-layer. R4: (1) agg software-pipelined 2-deep (ping-pong reg slots:
// FMA batch b while batch b+1 gathers and batch b+2 ep-loads in flight),
// predicated fixed batches kill the MLP-1 remainder loop. (2) gemm K-split
// into two 64-phases: LDS 97.8->49.4 KB = 3 blocks/CU (was 1). (3) parallel
// 3-kernel scan replaces single-block serial scan.

#define K_IN 128  // all layers have in_features == 128
#define FIX_SCALE 8388608.0f  // 2^23 fixed point for ew sums

// ---------- norm / CSR construction ----------

__global__ void init_kernel(unsigned long long* __restrict__ packed, int n) {
    int i = blockIdx.x * blockDim.x + threadIdx.x;
    if (i < n) packed[i] = 0ULL;
}

// one 64-bit atomic per edge; rank[i] = old count at dst (order within row)
__global__ void deg_kernel(const int* __restrict__ dst, const float* __restrict__ ew,
                           unsigned long long* __restrict__ packed,
                           int* __restrict__ rank, int e) {
    int i = blockIdx.x * blockDim.x + threadIdx.x;
    if (i >= e) return;
    int d = dst[i];
    unsigned long long fx = (unsigned long long)(unsigned int)(ew[i] * FIX_SCALE + 0.5f);
    unsigned long long inc = (fx << 32) | 1ULL;
    unsigned long long old = atomicAdd(&packed[d], inc);
    rank[i] = (int)(old & 0xffffffffULL);
}

__global__ void dinv_kernel(const unsigned long long* __restrict__ packed,
                            float* __restrict__ dinv, int n) {
    int i = blockIdx.x * blockDim.x + threadIdx.x;
    if (i >= n) return;
    float deg = 1.0f + (float)(packed[i] >> 32) * (1.0f / FIX_SCALE);  // +1 self loop
    dinv[i] = rsqrtf(deg);
}

// ---- parallel scan: A) per-block reduce, B) scan block sums, C) scan+write ----

__global__ __launch_bounds__(256) void reduce_kernel(const unsigned long long* __restrict__ packed,
                                                     int* __restrict__ bs, int n) {
    __shared__ int s[256];
    int t = threadIdx.x, i = blockIdx.x * 256 + t;
    s[t] = (i < n) ? (int)(packed[i] & 0xffffffffULL) : 0;
    __syncthreads();
    for (int off = 128; off > 0; off >>= 1) {
        if (t < off) s[t] += s[t + off];
        __syncthreads();
    }
    if (t == 0) bs[blockIdx.x] = s[0];
}

// nb <= 256 (N <= 65536)
__global__ __launch_bounds__(256) void scanb_kernel(const int* __restrict__ bs,
                                                    int* __restrict__ bo,
                                                    int* __restrict__ row_ptr,
                                                    int nb, int n) {
    __shared__ int s[256];
    int t = threadIdx.x;
    s[t] = (t < nb) ? bs[t] : 0;
    __syncthreads();
    for (int off = 1; off < 256; off <<= 1) {
        int cur = s[t];
        int add = (t >= off) ? s[t - off] : 0;
        __syncthreads();
        s[t] = cur + add;
        __syncthreads();
    }
    if (t < nb) bo[t] = (t == 0) ? 0 : s[t - 1];
    if (t == nb - 1) row_ptr[n] = s[t];
}

__global__ __launch_bounds__(256) void scanw_kernel(const unsigned long long* __restrict__ packed,
                                                    const int* __restrict__ bo,
                                                    int* __restrict__ row_ptr, int n) {
    __shared__ int s[256];
    int t = threadIdx.x, i = blockIdx.x * 256 + t;
    int c = (i < n) ? (int)(packed[i] & 0xffffffffULL) : 0;
    s[t] = c;
    __syncthreads();
    for (int off = 1; off < 256; off <<= 1) {
        int cur = s[t];
        int add = (t >= off) ? s[t - off] : 0;
        __syncthreads();
        s[t] = cur + add;
        __syncthreads();
    }
    if (i < n) row_ptr[i] = bo[blockIdx.x] + (s[t] - c);  // exclusive
}

// atomic-free fill: pos = row_ptr[dst] + rank
__global__ void fill_kernel(const int* __restrict__ src, const int* __restrict__ dst,
                            const float* __restrict__ ew, const float* __restrict__ dinv,
                            const int* __restrict__ row_ptr, const int* __restrict__ rank,
                            int2* __restrict__ ep, int e) {
    int i = blockIdx.x * blockDim.x + threadIdx.x;
    if (i >= e) return;
    int s = src[i], d = dst[i];
    int pos = row_ptr[d] + rank[i];
    float v = dinv[s] * ew[i] * dinv[d];
    ep[pos] = make_int2(s, __float_as_int(v));
}

// ---------- GEMM: H[n x NOUT] = X[n x 128] @ W[128 x NOUT] ----------
// K split into two 64-phases -> LDS 49.4 KB (NOUT=128) -> 3 blocks/CU.
template <int NOUT>
__global__ __launch_bounds__(256) void gemm_kernel(const float* __restrict__ X,
                                                   const float* __restrict__ W,
                                                   float* __restrict__ H, int n) {
    constexpr int CN = NOUT / 16;  // 8 (NOUT=128) or 4 (NOUT=64)
    __shared__ float Xs[64][68];
    __shared__ float Ws[64][NOUT];
    int t = threadIdx.x;
    int row0 = blockIdx.x * 64;
    int tx = t & 15, ty = t >> 4;
    int c0 = tx * CN;
    float acc[4][CN];
#pragma unroll
    for (int i = 0; i < 4; i++)
#pragma unroll
        for (int j = 0; j < CN; j++) acc[i][j] = 0.f;

    for (int kb = 0; kb < K_IN; kb += 64) {
        if (kb) __syncthreads();  // protect LDS reuse across phases
        for (int i = t; i < 64 * NOUT / 4; i += 256) {
            int k = (i * 4) / NOUT, c = (i * 4) % NOUT;
            *(float4*)&Ws[k][c] = *(const float4*)(W + (size_t)(kb + k) * NOUT + c);
        }
        for (int i = t; i < 64 * 16; i += 256) {
            int r = i >> 4, k = (i & 15) << 2;
            int row = row0 + r;
            float4 x4 = make_float4(0.f, 0.f, 0.f, 0.f);
            if (row < n) x4 = *(const float4*)(X + (size_t)row * K_IN + kb + k);
            *(float4*)&Xs[r][k] = x4;
        }
        __syncthreads();

        for (int k = 0; k < 64; k += 4) {
            float4 xv[4];
#pragma unroll
            for (int i = 0; i < 4; i++) xv[i] = *(const float4*)&Xs[ty + 16 * i][k];
#pragma unroll
            for (int kk = 0; kk < 4; kk++) {
                float wv[CN];
#pragma unroll
                for (int j = 0; j < CN; j += 4) {
                    float4 w4 = *(const float4*)&Ws[k + kk][c0 + j];
                    wv[j] = w4.x; wv[j + 1] = w4.y; wv[j + 2] = w4.z; wv[j + 3] = w4.w;
                }
#pragma unroll
                for (int i = 0; i < 4; i++) {
                    float xs = (kk == 0) ? xv[i].x : (kk == 1) ? xv[i].y
                              : (kk == 2) ? xv[i].z : xv[i].w;
#pragma unroll
                    for (int j = 0; j < CN; j++) acc[i][j] += xs * wv[j];
                }
            }
        }
    }

#pragma unroll
    for (int i = 0; i < 4; i++) {
        int row = row0 + ty + 16 * i;
        if (row < n) {
#pragma unroll
            for (int j = 0; j < CN; j += 4) {
                *(float4*)(H + (size_t)row * NOUT + c0 + j) =
                    make_float4(acc[i][j], acc[i][j + 1], acc[i][j + 2], acc[i][j + 3]);
            }
        }
    }
}

// ---------- aggregation ----------
// one wave per node; 2-deep software pipeline with ping-pong register slots.
// Batches are fixed UN=8 with clamp+zero-weight predication (no remainder).
template <int F, bool RELU>
__global__ __launch_bounds__(256) void agg_kernel(const float* __restrict__ H,
                                                  const int* __restrict__ row_ptr,
                                                  const int2* __restrict__ ep,
                                                  const float* __restrict__ dinv,
                                                  const float* __restrict__ bias,
                                                  float* __restrict__ out, int n) {
    constexpr int VPL = F / 64;  // 2 for F=128, 1 for F=64
    constexpr int UN = 8;
    int wid = threadIdx.x >> 6;
    int lane = threadIdx.x & 63;
    int node = blockIdx.x * 4 + wid;
    if (node >= n) return;

    int start = row_ptr[node], end = row_ptr[node + 1];
    float di = dinv[node];
    float sw = di * di;

    float acc[VPL];
    const float* hs = H + (size_t)node * F + lane * VPL;
#pragma unroll
    for (int j = 0; j < VPL; j++) acc[j] = hs[j] * sw;

    int len = end - start;
    if (len > 0) {
        int nb = (len + UN - 1) / UN;
        int2 eA[UN], eB[UN];
        float vA[UN][VPL], vB[UN][VPL];

        auto loadE = [&](int b, int2* e) {
            int base = start + b * UN;
#pragma unroll
            for (int u = 0; u < UN; u++) {
                int p = base + u;
                int q = (p < end) ? p : end - 1;
                int2 t2 = ep[q];
                if (p >= end) t2.y = 0;  // pad: zero weight
                e[u] = t2;
            }
        };
        auto gath = [&](const int2* e, float (*v)[VPL]) {
#pragma unroll
            for (int u = 0; u < UN; u++) {
                const float* hr = H + (size_t)e[u].x * F + lane * VPL;
#pragma unroll
                for (int j = 0; j < VPL; j++) v[u][j] = hr[j];
            }
        };
        auto fmas = [&](const int2* e, const float (*v)[VPL]) {
#pragma unroll
            for (int u = 0; u < UN; u++) {
                float w = __int_as_float(e[u].y);
#pragma unroll
                for (int j = 0; j < VPL; j++) acc[j] += w * v[u][j];
            }
        };

        loadE(0, eA);
        if (nb > 1) loadE(1, eB);
        gath(eA, vA);
        int b = 0;
        while (true) {
            // batch b in slot A
            if (b + 1 < nb) gath(eB, vB);      // batch b+1 gathers in flight
            fmas(eA, vA);                      // waits only on vA
            if (b + 2 < nb) loadE(b + 2, eA);  // batch b+2 ep in flight
            if (++b >= nb) break;
            // batch b in slot B
            if (b + 1 < nb) gath(eA, vA);
            fmas(eB, vB);
            if (b + 2 < nb) loadE(b + 2, eB);
            if (++b >= nb) break;
        }
    }

#pragma unroll
    for (int j = 0; j < VPL; j++) {
        float o = acc[j] + bias[lane * VPL + j];
        if (RELU) o = fmaxf(o, 0.f);
        out[(size_t)node * F + lane * VPL + j] = o;
    }
}

// ---------- launch ----------

extern "C" void kernel_launch(void* const* d_in, const int* in_sizes, int n_in,
                              void* d_out, int out_size, void* d_ws, size_t ws_size,
                              hipStream_t stream) {
    const float* x   = (const float*)d_in[0];
    const int*   ei  = (const int*)d_in[1];   // int32 (JAX x64 disabled)
    const float* ew  = (const float*)d_in[2];
    const float* W1  = (const float*)d_in[3];
    const float* b1  = (const float*)d_in[4];
    const float* W2  = (const float*)d_in[5];
    const float* b2  = (const float*)d_in[6];
    const float* W3  = (const float*)d_in[7];
    const float* b3  = (const float*)d_in[8];
    float* out = (float*)d_out;

    const int N = in_sizes[0] / K_IN;
    const int E = in_sizes[2];
    const int* src = ei;
    const int* dst = ei + E;

    char* w = (char*)d_ws;
    auto alloc = [&](size_t bytes) {
        void* p = (void*)w;
        w += (bytes + 255) & ~(size_t)255;
        return p;
    };
    unsigned long long* packed = (unsigned long long*)alloc((size_t)N * 8);
    float* dinv    = (float*)alloc((size_t)N * 4);
    int*   row_ptr = (int*)alloc((size_t)(N + 1) * 4);
    int*   rank    = (int*)alloc((size_t)E * 4);
    int2*  ep      = (int2*)alloc((size_t)E * 8);
    int*   bs      = (int*)alloc(((size_t)N / 256 + 2) * 4);
    int*   bo      = (int*)alloc(((size_t)N / 256 + 2) * 4);
    float* bufB    = (float*)alloc((size_t)N * 128 * 4);
    float* bufC    = (float*)alloc((size_t)N * 128 * 4);

    int gN = (N + 255) / 256;
    int gE = (E + 255) / 256;
    int nb = gN;  // scan blocks (<=256 for N<=65536)

    init_kernel<<<gN, 256, 0, stream>>>(packed, N);
    deg_kernel<<<gE, 256, 0, stream>>>(dst, ew, packed, rank, E);
    dinv_kernel<<<gN, 256, 0, stream>>>(packed, dinv, N);
    reduce_kernel<<<nb, 256, 0, stream>>>(packed, bs, N);
    scanb_kernel<<<1, 256, 0, stream>>>(bs, bo, row_ptr, nb, N);
    scanw_kernel<<<nb, 256, 0, stream>>>(packed, bo, row_ptr, N);
    fill_kernel<<<gE, 256, 0, stream>>>(src, dst, ew, dinv, row_ptr, rank, ep, E);

    int gGemm = (N + 63) / 64;
    int gAgg  = (N + 3) / 4;

    gemm_kernel<128><<<gGemm, 256, 0, stream>>>(x, W1, bufB, N);
    agg_kernel<128, true><<<gAgg, 256, 0, stream>>>(bufB, row_ptr, ep, dinv, b1, bufC, N);
    gemm_kernel<128><<<gGemm, 256, 0, stream>>>(bufC, W2, bufB, N);
    agg_kernel<128, true><<<gAgg, 256, 0, stream>>>(bufB, row_ptr, ep, dinv, b2, bufC, N);
    gemm_kernel<64><<<gGemm, 256, 0, stream>>>(bufC, W3, bufB, N);
    agg_kernel<64, false><<<gAgg, 256, 0, stream>>>(bufB, row_ptr, ep, dinv, b3, out, N);
}

// Round 5
// 465.868 us; speedup vs baseline: 2.2885x; 1.2697x over previous
//
#include <hip/hip_runtime.h>
#include <hip/hip_bf16.h>
#include <hip/hip_fp16.h>

// GCN 3-layer. R5: (1) REVERT R4's manual agg pipeline (regressed 108->118:
// predication VALU + VGPR 32->56 + occupancy 74->37%). (2) H stored fp16:
// gather row 512->256B, working set 25.6->12.8MB -> L2 hits up, FETCH ~halved.
// agg = R3 shape, UN=16, one predicated tail batch. fp32 accumulate everywhere.

#define K_IN 128  // all layers have in_features == 128
#define FIX_SCALE 8388608.0f  // 2^23 fixed point for ew sums

// ---------- norm / CSR construction ----------

__global__ void init_kernel(unsigned long long* __restrict__ packed, int n) {
    int i = blockIdx.x * blockDim.x + threadIdx.x;
    if (i < n) packed[i] = 0ULL;
}

// one 64-bit atomic per edge; rank[i] = old count at dst (order within row)
__global__ void deg_kernel(const int* __restrict__ dst, const float* __restrict__ ew,
                           unsigned long long* __restrict__ packed,
                           int* __restrict__ rank, int e) {
    int i = blockIdx.x * blockDim.x + threadIdx.x;
    if (i >= e) return;
    int d = dst[i];
    unsigned long long fx = (unsigned long long)(unsigned int)(ew[i] * FIX_SCALE + 0.5f);
    unsigned long long inc = (fx << 32) | 1ULL;
    unsigned long long old = atomicAdd(&packed[d], inc);
    rank[i] = (int)(old & 0xffffffffULL);
}

__global__ void dinv_kernel(const unsigned long long* __restrict__ packed,
                            float* __restrict__ dinv, int n) {
    int i = blockIdx.x * blockDim.x + threadIdx.x;
    if (i >= n) return;
    float deg = 1.0f + (float)(packed[i] >> 32) * (1.0f / FIX_SCALE);  // +1 self loop
    dinv[i] = rsqrtf(deg);
}

// ---- parallel scan: A) per-block reduce, B) scan block sums, C) scan+write ----

__global__ __launch_bounds__(256) void reduce_kernel(const unsigned long long* __restrict__ packed,
                                                     int* __restrict__ bs, int n) {
    __shared__ int s[256];
    int t = threadIdx.x, i = blockIdx.x * 256 + t;
    s[t] = (i < n) ? (int)(packed[i] & 0xffffffffULL) : 0;
    __syncthreads();
    for (int off = 128; off > 0; off >>= 1) {
        if (t < off) s[t] += s[t + off];
        __syncthreads();
    }
    if (t == 0) bs[blockIdx.x] = s[0];
}

// nb <= 256 (N <= 65536)
__global__ __launch_bounds__(256) void scanb_kernel(const int* __restrict__ bs,
                                                    int* __restrict__ bo,
                                                    int* __restrict__ row_ptr,
                                                    int nb, int n) {
    __shared__ int s[256];
    int t = threadIdx.x;
    s[t] = (t < nb) ? bs[t] : 0;
    __syncthreads();
    for (int off = 1; off < 256; off <<= 1) {
        int cur = s[t];
        int add = (t >= off) ? s[t - off] : 0;
        __syncthreads();
        s[t] = cur + add;
        __syncthreads();
    }
    if (t < nb) bo[t] = (t == 0) ? 0 : s[t - 1];
    if (t == nb - 1) row_ptr[n] = s[t];
}

__global__ __launch_bounds__(256) void scanw_kernel(const unsigned long long* __restrict__ packed,
                                                    const int* __restrict__ bo,
                                                    int* __restrict__ row_ptr, int n) {
    __shared__ int s[256];
    int t = threadIdx.x, i = blockIdx.x * 256 + t;
    int c = (i < n) ? (int)(packed[i] & 0xffffffffULL) : 0;
    s[t] = c;
    __syncthreads();
    for (int off = 1; off < 256; off <<= 1) {
        int cur = s[t];
        int add = (t >= off) ? s[t - off] : 0;
        __syncthreads();
        s[t] = cur + add;
        __syncthreads();
    }
    if (i < n) row_ptr[i] = bo[blockIdx.x] + (s[t] - c);  // exclusive
}

// atomic-free fill: pos = row_ptr[dst] + rank
__global__ void fill_kernel(const int* __restrict__ src, const int* __restrict__ dst,
                            const float* __restrict__ ew, const float* __restrict__ dinv,
                            const int* __restrict__ row_ptr, const int* __restrict__ rank,
                            int2* __restrict__ ep, int e) {
    int i = blockIdx.x * blockDim.x + threadIdx.x;
    if (i >= e) return;
    int s = src[i], d = dst[i];
    int pos = row_ptr[d] + rank[i];
    float v = dinv[s] * ew[i] * dinv[d];
    ep[pos] = make_int2(s, __float_as_int(v));
}

// ---------- GEMM: H[n x NOUT](fp16) = X[n x 128](fp32) @ W[128 x NOUT] ----------
// K split into two 64-phases -> LDS 49.4 KB (NOUT=128) -> 3 blocks/CU.
template <int NOUT>
__global__ __launch_bounds__(256) void gemm_kernel(const float* __restrict__ X,
                                                   const float* __restrict__ W,
                                                   __half* __restrict__ H, int n) {
    constexpr int CN = NOUT / 16;  // 8 (NOUT=128) or 4 (NOUT=64)
    __shared__ float Xs[64][68];
    __shared__ float Ws[64][NOUT];
    int t = threadIdx.x;
    int row0 = blockIdx.x * 64;
    int tx = t & 15, ty = t >> 4;
    int c0 = tx * CN;
    float acc[4][CN];
#pragma unroll
    for (int i = 0; i < 4; i++)
#pragma unroll
        for (int j = 0; j < CN; j++) acc[i][j] = 0.f;

    for (int kb = 0; kb < K_IN; kb += 64) {
        if (kb) __syncthreads();
        for (int i = t; i < 64 * NOUT / 4; i += 256) {
            int k = (i * 4) / NOUT, c = (i * 4) % NOUT;
            *(float4*)&Ws[k][c] = *(const float4*)(W + (size_t)(kb + k) * NOUT + c);
        }
        for (int i = t; i < 64 * 16; i += 256) {
            int r = i >> 4, k = (i & 15) << 2;
            int row = row0 + r;
            float4 x4 = make_float4(0.f, 0.f, 0.f, 0.f);
            if (row < n) x4 = *(const float4*)(X + (size_t)row * K_IN + kb + k);
            *(float4*)&Xs[r][k] = x4;
        }
        __syncthreads();

        for (int k = 0; k < 64; k += 4) {
            float4 xv[4];
#pragma unroll
            for (int i = 0; i < 4; i++) xv[i] = *(const float4*)&Xs[ty + 16 * i][k];
#pragma unroll
            for (int kk = 0; kk < 4; kk++) {
                float wv[CN];
#pragma unroll
                for (int j = 0; j < CN; j += 4) {
                    float4 w4 = *(const float4*)&Ws[k + kk][c0 + j];
                    wv[j] = w4.x; wv[j + 1] = w4.y; wv[j + 2] = w4.z; wv[j + 3] = w4.w;
                }
#pragma unroll
                for (int i = 0; i < 4; i++) {
                    float xs = (kk == 0) ? xv[i].x : (kk == 1) ? xv[i].y
                              : (kk == 2) ? xv[i].z : xv[i].w;
#pragma unroll
                    for (int j = 0; j < CN; j++) acc[i][j] += xs * wv[j];
                }
            }
        }
    }

#pragma unroll
    for (int i = 0; i < 4; i++) {
        int row = row0 + ty + 16 * i;
        if (row < n) {
            __half2 ph[CN / 2];
#pragma unroll
            for (int j = 0; j < CN / 2; j++)
                ph[j] = __floats2half2_rn(acc[i][2 * j], acc[i][2 * j + 1]);
            __half* dst = H + (size_t)row * NOUT + c0;
            if (CN == 8)
                *reinterpret_cast<uint4*>(dst) = *reinterpret_cast<uint4*>(ph);
            else
                *reinterpret_cast<uint2*>(dst) = *reinterpret_cast<uint2*>(ph);
        }
    }
}

// ---------- aggregation: fp16 gathers, fp32 accumulate ----------
// one wave per node; UN=16 batch loop (R3 shape) + ONE predicated tail batch.
template <int F, bool RELU>
__global__ __launch_bounds__(256) void agg_kernel(const __half* __restrict__ H,
                                                  const int* __restrict__ row_ptr,
                                                  const int2* __restrict__ ep,
                                                  const float* __restrict__ dinv,
                                                  const float* __restrict__ bias,
                                                  float* __restrict__ out, int n) {
    constexpr int UN = 16;
    int wid = threadIdx.x >> 6;
    int lane = threadIdx.x & 63;
    int node = blockIdx.x * 4 + wid;
    if (node >= n) return;

    int start = row_ptr[node], end = row_ptr[node + 1];
    float di = dinv[node];
    float sw = di * di;

    float a0, a1;
    if (F == 128) {
        float2 s2 = __half22float2(((const __half2*)(H + (size_t)node * 128))[lane]);
        a0 = s2.x * sw; a1 = s2.y * sw;
    } else {
        a0 = __half2float(H[(size_t)node * 64 + lane]) * sw; a1 = 0.f;
    }

    int len = end - start;
    int nf = len / UN;
    const int2* pp = ep + start;
    for (int b = 0; b < nf; b++, pp += UN) {
        int2 e[UN];
#pragma unroll
        for (int u = 0; u < UN; u++) e[u] = pp[u];
        __half2 v2[UN];
        __half v1[UN];
#pragma unroll
        for (int u = 0; u < UN; u++) {
            if (F == 128) v2[u] = ((const __half2*)(H + (size_t)e[u].x * 128))[lane];
            else          v1[u] = H[(size_t)e[u].x * 64 + lane];
        }
#pragma unroll
        for (int u = 0; u < UN; u++) {
            float w = __int_as_float(e[u].y);
            if (F == 128) {
                float2 f = __half22float2(v2[u]);
                a0 += w * f.x; a1 += w * f.y;
            } else {
                a0 += w * __half2float(v1[u]);
            }
        }
    }
    int base = start + nf * UN;
    if (base < end) {  // single predicated tail batch (full MLP on remainder)
        int2 e[UN];
#pragma unroll
        for (int u = 0; u < UN; u++) {
            int p = base + u;
            int q = (p < end) ? p : end - 1;
            int2 t2 = ep[q];
            if (p >= end) t2.y = 0;
            e[u] = t2;
        }
        __half2 v2[UN];
        __half v1[UN];
#pragma unroll
        for (int u = 0; u < UN; u++) {
            if (F == 128) v2[u] = ((const __half2*)(H + (size_t)e[u].x * 128))[lane];
            else          v1[u] = H[(size_t)e[u].x * 64 + lane];
        }
#pragma unroll
        for (int u = 0; u < UN; u++) {
            float w = __int_as_float(e[u].y);
            if (F == 128) {
                float2 f = __half22float2(v2[u]);
                a0 += w * f.x; a1 += w * f.y;
            } else {
                a0 += w * __half2float(v1[u]);
            }
        }
    }

    if (F == 128) {
        float o0 = a0 + bias[lane * 2];
        float o1 = a1 + bias[lane * 2 + 1];
        if (RELU) { o0 = fmaxf(o0, 0.f); o1 = fmaxf(o1, 0.f); }
        *(float2*)(out + (size_t)node * 128 + lane * 2) = make_float2(o0, o1);
    } else {
        float o = a0 + bias[lane];
        if (RELU) o = fmaxf(o, 0.f);
        out[(size_t)node * 64 + lane] = o;
    }
}

// ---------- launch ----------

extern "C" void kernel_launch(void* const* d_in, const int* in_sizes, int n_in,
                              void* d_out, int out_size, void* d_ws, size_t ws_size,
                              hipStream_t stream) {
    const float* x   = (const float*)d_in[0];
    const int*   ei  = (const int*)d_in[1];   // int32 (JAX x64 disabled)
    const float* ew  = (const float*)d_in[2];
    const float* W1  = (const float*)d_in[3];
    const float* b1  = (const float*)d_in[4];
    const float* W2  = (const float*)d_in[5];
    const float* b2  = (const float*)d_in[6];
    const float* W3  = (const float*)d_in[7];
    const float* b3  = (const float*)d_in[8];
    float* out = (float*)d_out;

    const int N = in_sizes[0] / K_IN;
    const int E = in_sizes[2];
    const int* src = ei;
    const int* dst = ei + E;

    char* w = (char*)d_ws;
    auto alloc = [&](size_t bytes) {
        void* p = (void*)w;
        w += (bytes + 255) & ~(size_t)255;
        return p;
    };
    unsigned long long* packed = (unsigned long long*)alloc((size_t)N * 8);
    float*  dinv    = (float*)alloc((size_t)N * 4);
    int*    row_ptr = (int*)alloc((size_t)(N + 1) * 4);
    int*    rank    = (int*)alloc((size_t)E * 4);
    int2*   ep      = (int2*)alloc((size_t)E * 8);
    int*    bs      = (int*)alloc(((size_t)N / 256 + 2) * 4);
    int*    bo      = (int*)alloc(((size_t)N / 256 + 2) * 4);
    __half* bufH    = (__half*)alloc((size_t)N * 128 * 2);  // gemm out (fp16)
    float*  bufC    = (float*)alloc((size_t)N * 128 * 4);   // agg out (fp32)

    int gN = (N + 255) / 256;
    int gE = (E + 255) / 256;
    int nb = gN;  // scan blocks (<=256 for N<=65536)

    init_kernel<<<gN, 256, 0, stream>>>(packed, N);
    deg_kernel<<<gE, 256, 0, stream>>>(dst, ew, packed, rank, E);
    dinv_kernel<<<gN, 256, 0, stream>>>(packed, dinv, N);
    reduce_kernel<<<nb, 256, 0, stream>>>(packed, bs, N);
    scanb_kernel<<<1, 256, 0, stream>>>(bs, bo, row_ptr, nb, N);
    scanw_kernel<<<nb, 256, 0, stream>>>(packed, bo, row_ptr, N);
    fill_kernel<<<gE, 256, 0, stream>>>(src, dst, ew, dinv, row_ptr, rank, ep, E);

    int gGemm = (N + 63) / 64;
    int gAgg  = (N + 3) / 4;

    gemm_kernel<128><<<gGemm, 256, 0, stream>>>(x, W1, bufH, N);
    agg_kernel<128, true><<<gAgg, 256, 0, stream>>>(bufH, row_ptr, ep, dinv, b1, bufC, N);
    gemm_kernel<128><<<gGemm, 256, 0, stream>>>(bufC, W2, bufH, N);
    agg_kernel<128, true><<<gAgg, 256, 0, stream>>>(bufH, row_ptr, ep, dinv, b2, bufC, N);
    gemm_kernel<64><<<gGemm, 256, 0, stream>>>(bufC, W3, bufH, N);
    agg_kernel<64, false><<<gAgg, 256, 0, stream>>>(bufH, row_ptr, ep, dinv, b3, out, N);
}

// Round 6
// 462.241 us; speedup vs baseline: 2.3065x; 1.0078x over previous
//
#include <hip/hip_runtime.h>
#include <hip/hip_bf16.h>
#include <hip/hip_fp16.h>

// GCN 3-layer. R6: XCD-replicated CSR-build atomics. deg_kernel was 76us at
// VALUBusy 0.6% — 1.6M 64-bit atomics onto 400KB (~6250 lines, ~256 ops/line,
// from all 8 XCDs, cross-XCD same-line serialization). Now 8 replicas
// (replica = blockIdx&7, matching round-robin block->XCD): 8x more lines,
// single-XCD per line. node_kernel computes per-node replica prefix + cnt +
// dinv; fill places at row_ptr[d] + rep_base[r][d] + rank_in_replica.

#define K_IN 128  // all layers have in_features == 128
#define FIX_SCALE 8388608.0f  // 2^23 fixed point for ew sums
#define NREP 8

// ---------- norm / CSR construction ----------

__global__ void init_kernel(unsigned long long* __restrict__ packed, int n8) {
    int i = blockIdx.x * blockDim.x + threadIdx.x;
    if (i < n8) packed[i] = 0ULL;
}

// one 64-bit atomic per edge into this block's XCD replica;
// rank[i] = old count within (replica, dst)
__global__ void deg_kernel(const int* __restrict__ dst, const float* __restrict__ ew,
                           unsigned long long* __restrict__ packed_r,
                           int* __restrict__ rank, int n, int e) {
    int i = blockIdx.x * blockDim.x + threadIdx.x;
    if (i >= e) return;
    int r = blockIdx.x & (NREP - 1);
    int d = dst[i];
    unsigned long long fx = (unsigned long long)(unsigned int)(ew[i] * FIX_SCALE + 0.5f);
    unsigned long long inc = (fx << 32) | 1ULL;
    unsigned long long old = atomicAdd(&packed_r[(size_t)r * n + d], inc);
    rank[i] = (int)(old & 0xffffffffULL);
}

// per-node: replica prefix (rep_base), total count (cnt), dinv
__global__ void node_kernel(const unsigned long long* __restrict__ packed_r,
                            float* __restrict__ dinv, int* __restrict__ cnt,
                            int* __restrict__ rep_base, int n) {
    int d = blockIdx.x * blockDim.x + threadIdx.x;
    if (d >= n) return;
    int c = 0;
    unsigned int s = 0;  // total fx sum: deg<~100 -> < 100*2^23 < 2^32
#pragma unroll
    for (int r = 0; r < NREP; r++) {
        unsigned long long p = packed_r[(size_t)r * n + d];
        rep_base[(size_t)r * n + d] = c;
        c += (int)(p & 0xffffffffULL);
        s += (unsigned int)(p >> 32);
    }
    cnt[d] = c;
    dinv[d] = rsqrtf(1.0f + (float)s * (1.0f / FIX_SCALE));  // +1 self loop
}

// ---- parallel scan over cnt: A) per-block reduce, B) scan sums, C) scan+write ----

__global__ __launch_bounds__(256) void reduce_kernel(const int* __restrict__ cnt,
                                                     int* __restrict__ bs, int n) {
    __shared__ int s[256];
    int t = threadIdx.x, i = blockIdx.x * 256 + t;
    s[t] = (i < n) ? cnt[i] : 0;
    __syncthreads();
    for (int off = 128; off > 0; off >>= 1) {
        if (t < off) s[t] += s[t + off];
        __syncthreads();
    }
    if (t == 0) bs[blockIdx.x] = s[0];
}

// nb <= 256 (N <= 65536)
__global__ __launch_bounds__(256) void scanb_kernel(const int* __restrict__ bs,
                                                    int* __restrict__ bo,
                                                    int* __restrict__ row_ptr,
                                                    int nb, int n) {
    __shared__ int s[256];
    int t = threadIdx.x;
    s[t] = (t < nb) ? bs[t] : 0;
    __syncthreads();
    for (int off = 1; off < 256; off <<= 1) {
        int cur = s[t];
        int add = (t >= off) ? s[t - off] : 0;
        __syncthreads();
        s[t] = cur + add;
        __syncthreads();
    }
    if (t < nb) bo[t] = (t == 0) ? 0 : s[t - 1];
    if (t == nb - 1) row_ptr[n] = s[t];
}

__global__ __launch_bounds__(256) void scanw_kernel(const int* __restrict__ cnt,
                                                    const int* __restrict__ bo,
                                                    int* __restrict__ row_ptr, int n) {
    __shared__ int s[256];
    int t = threadIdx.x, i = blockIdx.x * 256 + t;
    int c = (i < n) ? cnt[i] : 0;
    s[t] = c;
    __syncthreads();
    for (int off = 1; off < 256; off <<= 1) {
        int cur = s[t];
        int add = (t >= off) ? s[t - off] : 0;
        __syncthreads();
        s[t] = cur + add;
        __syncthreads();
    }
    if (i < n) row_ptr[i] = bo[blockIdx.x] + (s[t] - c);  // exclusive
}

// atomic-free fill: pos = row_ptr[dst] + rep_base[replica][dst] + rank
__global__ void fill_kernel(const int* __restrict__ src, const int* __restrict__ dst,
                            const float* __restrict__ ew, const float* __restrict__ dinv,
                            const int* __restrict__ row_ptr, const int* __restrict__ rep_base,
                            const int* __restrict__ rank, int2* __restrict__ ep,
                            int n, int e) {
    int i = blockIdx.x * blockDim.x + threadIdx.x;
    if (i >= e) return;
    int r = blockIdx.x & (NREP - 1);  // same mapping as deg_kernel
    int s = src[i], d = dst[i];
    int pos = row_ptr[d] + rep_base[(size_t)r * n + d] + rank[i];
    float v = dinv[s] * ew[i] * dinv[d];
    ep[pos] = make_int2(s, __float_as_int(v));
}

// ---------- GEMM: H[n x NOUT](fp16) = X[n x 128](fp32) @ W[128 x NOUT] ----------
// K split into two 64-phases -> LDS 49.4 KB (NOUT=128) -> 3 blocks/CU.
template <int NOUT>
__global__ __launch_bounds__(256) void gemm_kernel(const float* __restrict__ X,
                                                   const float* __restrict__ W,
                                                   __half* __restrict__ H, int n) {
    constexpr int CN = NOUT / 16;  // 8 (NOUT=128) or 4 (NOUT=64)
    __shared__ float Xs[64][68];
    __shared__ float Ws[64][NOUT];
    int t = threadIdx.x;
    int row0 = blockIdx.x * 64;
    int tx = t & 15, ty = t >> 4;
    int c0 = tx * CN;
    float acc[4][CN];
#pragma unroll
    for (int i = 0; i < 4; i++)
#pragma unroll
        for (int j = 0; j < CN; j++) acc[i][j] = 0.f;

    for (int kb = 0; kb < K_IN; kb += 64) {
        if (kb) __syncthreads();
        for (int i = t; i < 64 * NOUT / 4; i += 256) {
            int k = (i * 4) / NOUT, c = (i * 4) % NOUT;
            *(float4*)&Ws[k][c] = *(const float4*)(W + (size_t)(kb + k) * NOUT + c);
        }
        for (int i = t; i < 64 * 16; i += 256) {
            int r = i >> 4, k = (i & 15) << 2;
            int row = row0 + r;
            float4 x4 = make_float4(0.f, 0.f, 0.f, 0.f);
            if (row < n) x4 = *(const float4*)(X + (size_t)row * K_IN + kb + k);
            *(float4*)&Xs[r][k] = x4;
        }
        __syncthreads();

        for (int k = 0; k < 64; k += 4) {
            float4 xv[4];
#pragma unroll
            for (int i = 0; i < 4; i++) xv[i] = *(const float4*)&Xs[ty + 16 * i][k];
#pragma unroll
            for (int kk = 0; kk < 4; kk++) {
                float wv[CN];
#pragma unroll
                for (int j = 0; j < CN; j += 4) {
                    float4 w4 = *(const float4*)&Ws[k + kk][c0 + j];
                    wv[j] = w4.x; wv[j + 1] = w4.y; wv[j + 2] = w4.z; wv[j + 3] = w4.w;
                }
#pragma unroll
                for (int i = 0; i < 4; i++) {
                    float xs = (kk == 0) ? xv[i].x : (kk == 1) ? xv[i].y
                              : (kk == 2) ? xv[i].z : xv[i].w;
#pragma unroll
                    for (int j = 0; j < CN; j++) acc[i][j] += xs * wv[j];
                }
            }
        }
    }

#pragma unroll
    for (int i = 0; i < 4; i++) {
        int row = row0 + ty + 16 * i;
        if (row < n) {
            __half2 ph[CN / 2];
#pragma unroll
            for (int j = 0; j < CN / 2; j++)
                ph[j] = __floats2half2_rn(acc[i][2 * j], acc[i][2 * j + 1]);
            __half* dstp = H + (size_t)row * NOUT + c0;
            if (CN == 8)
                *reinterpret_cast<uint4*>(dstp) = *reinterpret_cast<uint4*>(ph);
            else
                *reinterpret_cast<uint2*>(dstp) = *reinterpret_cast<uint2*>(ph);
        }
    }
}

// ---------- aggregation: fp16 gathers, fp32 accumulate ----------
// one wave per node; UN=16 batch loop + ONE predicated tail batch.
template <int F, bool RELU>
__global__ __launch_bounds__(256) void agg_kernel(const __half* __restrict__ H,
                                                  const int* __restrict__ row_ptr,
                                                  const int2* __restrict__ ep,
                                                  const float* __restrict__ dinv,
                                                  const float* __restrict__ bias,
                                                  float* __restrict__ out, int n) {
    constexpr int UN = 16;
    int wid = threadIdx.x >> 6;
    int lane = threadIdx.x & 63;
    int node = blockIdx.x * 4 + wid;
    if (node >= n) return;

    int start = row_ptr[node], end = row_ptr[node + 1];
    float di = dinv[node];
    float sw = di * di;

    float a0, a1;
    if (F == 128) {
        float2 s2 = __half22float2(((const __half2*)(H + (size_t)node * 128))[lane]);
        a0 = s2.x * sw; a1 = s2.y * sw;
    } else {
        a0 = __half2float(H[(size_t)node * 64 + lane]) * sw; a1 = 0.f;
    }

    int len = end - start;
    int nf = len / UN;
    const int2* pp = ep + start;
    for (int b = 0; b < nf; b++, pp += UN) {
        int2 e[UN];
#pragma unroll
        for (int u = 0; u < UN; u++) e[u] = pp[u];
        __half2 v2[UN];
        __half v1[UN];
#pragma unroll
        for (int u = 0; u < UN; u++) {
            if (F == 128) v2[u] = ((const __half2*)(H + (size_t)e[u].x * 128))[lane];
            else          v1[u] = H[(size_t)e[u].x * 64 + lane];
        }
#pragma unroll
        for (int u = 0; u < UN; u++) {
            float w = __int_as_float(e[u].y);
            if (F == 128) {
                float2 f = __half22float2(v2[u]);
                a0 += w * f.x; a1 += w * f.y;
            } else {
                a0 += w * __half2float(v1[u]);
            }
        }
    }
    int base = start + nf * UN;
    if (base < end) {  // single predicated tail batch
        int2 e[UN];
#pragma unroll
        for (int u = 0; u < UN; u++) {
            int p = base + u;
            int q = (p < end) ? p : end - 1;
            int2 t2 = ep[q];
            if (p >= end) t2.y = 0;
            e[u] = t2;
        }
        __half2 v2[UN];
        __half v1[UN];
#pragma unroll
        for (int u = 0; u < UN; u++) {
            if (F == 128) v2[u] = ((const __half2*)(H + (size_t)e[u].x * 128))[lane];
            else          v1[u] = H[(size_t)e[u].x * 64 + lane];
        }
#pragma unroll
        for (int u = 0; u < UN; u++) {
            float w = __int_as_float(e[u].y);
            if (F == 128) {
                float2 f = __half22float2(v2[u]);
                a0 += w * f.x; a1 += w * f.y;
            } else {
                a0 += w * __half2float(v1[u]);
            }
        }
    }

    if (F == 128) {
        float o0 = a0 + bias[lane * 2];
        float o1 = a1 + bias[lane * 2 + 1];
        if (RELU) { o0 = fmaxf(o0, 0.f); o1 = fmaxf(o1, 0.f); }
        *(float2*)(out + (size_t)node * 128 + lane * 2) = make_float2(o0, o1);
    } else {
        float o = a0 + bias[lane];
        if (RELU) o = fmaxf(o, 0.f);
        out[(size_t)node * 64 + lane] = o;
    }
}

// ---------- launch ----------

extern "C" void kernel_launch(void* const* d_in, const int* in_sizes, int n_in,
                              void* d_out, int out_size, void* d_ws, size_t ws_size,
                              hipStream_t stream) {
    const float* x   = (const float*)d_in[0];
    const int*   ei  = (const int*)d_in[1];   // int32 (JAX x64 disabled)
    const float* ew  = (const float*)d_in[2];
    const float* W1  = (const float*)d_in[3];
    const float* b1  = (const float*)d_in[4];
    const float* W2  = (const float*)d_in[5];
    const float* b2  = (const float*)d_in[6];
    const float* W3  = (const float*)d_in[7];
    const float* b3  = (const float*)d_in[8];
    float* out = (float*)d_out;

    const int N = in_sizes[0] / K_IN;
    const int E = in_sizes[2];
    const int* src = ei;
    const int* dst = ei + E;

    char* w = (char*)d_ws;
    auto alloc = [&](size_t bytes) {
        void* p = (void*)w;
        w += (bytes + 255) & ~(size_t)255;
        return p;
    };
    unsigned long long* packed_r = (unsigned long long*)alloc((size_t)NREP * N * 8);
    float*  dinv    = (float*)alloc((size_t)N * 4);
    int*    cnt     = (int*)alloc((size_t)N * 4);
    int*    rep_base= (int*)alloc((size_t)NREP * N * 4);
    int*    row_ptr = (int*)alloc((size_t)(N + 1) * 4);
    int*    rank    = (int*)alloc((size_t)E * 4);
    int2*   ep      = (int2*)alloc((size_t)E * 8);
    int*    bs      = (int*)alloc(((size_t)N / 256 + 2) * 4);
    int*    bo      = (int*)alloc(((size_t)N / 256 + 2) * 4);
    __half* bufH    = (__half*)alloc((size_t)N * 128 * 2);  // gemm out (fp16)
    float*  bufC    = (float*)alloc((size_t)N * 128 * 4);   // agg out (fp32)

    int gN = (N + 255) / 256;
    int gE = (E + 255) / 256;
    int nb = gN;  // scan blocks (<=256 for N<=65536)

    init_kernel<<<(NREP * N + 255) / 256, 256, 0, stream>>>(packed_r, NREP * N);
    deg_kernel<<<gE, 256, 0, stream>>>(dst, ew, packed_r, rank, N, E);
    node_kernel<<<gN, 256, 0, stream>>>(packed_r, dinv, cnt, rep_base, N);
    reduce_kernel<<<nb, 256, 0, stream>>>(cnt, bs, N);
    scanb_kernel<<<1, 256, 0, stream>>>(bs, bo, row_ptr, nb, N);
    scanw_kernel<<<nb, 256, 0, stream>>>(cnt, bo, row_ptr, N);
    fill_kernel<<<gE, 256, 0, stream>>>(src, dst, ew, dinv, row_ptr, rep_base, rank, ep, N, E);

    int gGemm = (N + 63) / 64;
    int gAgg  = (N + 3) / 4;

    gemm_kernel<128><<<gGemm, 256, 0, stream>>>(x, W1, bufH, N);
    agg_kernel<128, true><<<gAgg, 256, 0, stream>>>(bufH, row_ptr, ep, dinv, b1, bufC, N);
    gemm_kernel<128><<<gGemm, 256, 0, stream>>>(bufC, W2, bufH, N);
    agg_kernel<128, true><<<gAgg, 256, 0, stream>>>(bufH, row_ptr, ep, dinv, b2, bufC, N);
    gemm_kernel<64><<<gGemm, 256, 0, stream>>>(bufC, W3, bufH, N);
    agg_kernel<64, false><<<gAgg, 256, 0, stream>>>(bufH, row_ptr, ep, dinv, b3, out, N);
}

// Round 7
// 416.966 us; speedup vs baseline: 2.5569x; 1.1086x over previous
//
#include <hip/hip_runtime.h>
#include <hip/hip_bf16.h>
#include <hip/hip_fp16.h>

// GCN 3-layer. R7: atomic-free CSR build. Evidence: global atomics cap at
// ~22G ops/s device-wide regardless of address spread (R2: 3.2M=144us,
// R3/R6: 1.6M=72-76us, XCD replication no help). Replaced deg+fill with a
// deterministic two-level counting sort: LDS-histogram partition (196
// buckets = dst>>8) + parallel scan of per-(bucket,block) counts + scatter +
// per-bucket LDS CSR finalize. Zero global atomics anywhere. gemm/agg from
// R5 unchanged (fp16 H gathers, fp32 accumulate).

#define K_IN 128              // all layers have in_features == 128
#define FIX_SCALE 8388608.0f  // 2^23 fixed point for ew sums
#define CE 4096               // edges per partition block (1024 thr x 4)

// ---------- pass 1: per-block bucket histogram + local rank ----------
__global__ __launch_bounds__(1024) void part_count(const int* __restrict__ dst,
                                                   int* __restrict__ counts,
                                                   unsigned short* __restrict__ lrank,
                                                   int nb, int nblk, int e) {
    __shared__ int c[256];  // nb <= 256
    int t = threadIdx.x, blk = blockIdx.x;
    for (int i = t; i < nb; i += 1024) c[i] = 0;
    __syncthreads();
    int b0 = blk * CE;
#pragma unroll
    for (int j = 0; j < 4; j++) {
        int i = b0 + j * 1024 + t;
        if (i < e) {
            int b = dst[i] >> 8;
            int r = atomicAdd(&c[b], 1);  // LDS atomic
            lrank[i] = (unsigned short)r;
        }
    }
    __syncthreads();
    for (int i = t; i < nb; i += 1024) counts[(size_t)i * nblk + blk] = c[i];
}

// ---------- pass 2: parallel exclusive scan over counts[nb*nblk] ----------
__global__ __launch_bounds__(256) void reduce_kernel(const int* __restrict__ v,
                                                     int* __restrict__ bs, int m) {
    __shared__ int s[256];
    int t = threadIdx.x, i = blockIdx.x * 256 + t;
    s[t] = (i < m) ? v[i] : 0;
    __syncthreads();
    for (int off = 128; off > 0; off >>= 1) {
        if (t < off) s[t] += s[t + off];
        __syncthreads();
    }
    if (t == 0) bs[blockIdx.x] = s[0];
}

__global__ __launch_bounds__(1024) void scanb1024(const int* __restrict__ bs,
                                                  int* __restrict__ bo, int nbb) {
    __shared__ int s[1024];
    int t = threadIdx.x;
    s[t] = (t < nbb) ? bs[t] : 0;
    __syncthreads();
    for (int off = 1; off < 1024; off <<= 1) {
        int cur = s[t];
        int add = (t >= off) ? s[t - off] : 0;
        __syncthreads();
        s[t] = cur + add;
        __syncthreads();
    }
    if (t < nbb) bo[t] = (t == 0) ? 0 : s[t - 1];
}

__global__ __launch_bounds__(256) void scanw_kernel(const int* __restrict__ v,
                                                    const int* __restrict__ bo,
                                                    int* __restrict__ outp, int m) {
    __shared__ int s[256];
    int t = threadIdx.x, i = blockIdx.x * 256 + t;
    int c = (i < m) ? v[i] : 0;
    s[t] = c;
    __syncthreads();
    for (int off = 1; off < 256; off <<= 1) {
        int cur = s[t];
        int add = (t >= off) ? s[t - off] : 0;
        __syncthreads();
        s[t] = cur + add;
        __syncthreads();
    }
    if (i < m) outp[i] = bo[blockIdx.x] + (s[t] - c);  // exclusive
}

// ---------- pass 3: scatter into bucket-sorted order ----------
__global__ __launch_bounds__(1024) void part_scatter(const int* __restrict__ src,
                                                     const int* __restrict__ dst,
                                                     const float* __restrict__ ew,
                                                     const int* __restrict__ base,
                                                     const unsigned short* __restrict__ lrank,
                                                     int2* __restrict__ arr1,
                                                     unsigned char* __restrict__ dlow,
                                                     int nblk, int e) {
    int t = threadIdx.x, blk = blockIdx.x;
    int b0 = blk * CE;
#pragma unroll
    for (int j = 0; j < 4; j++) {
        int i = b0 + j * 1024 + t;
        if (i < e) {
            int d = dst[i];
            int b = d >> 8;
            int pos = base[(size_t)b * nblk + blk] + lrank[i];
            arr1[pos] = make_int2(src[i], __float_as_int(ew[i]));
            dlow[pos] = (unsigned char)(d & 255);
        }
    }
}

// ---------- pass 4: per-bucket CSR finalize (row_ptr, dinv, ep w/ dinv[d]) ----------
__global__ __launch_bounds__(1024) void bucket_csr(const int2* __restrict__ arr1,
                                                   const unsigned char* __restrict__ dlow,
                                                   const int* __restrict__ base,
                                                   unsigned short* __restrict__ rank2,
                                                   float* __restrict__ dinv,
                                                   int* __restrict__ row_ptr,
                                                   int2* __restrict__ ep,
                                                   int nb, int nblk, int n, int e) {
    __shared__ int cnt2[256];
    __shared__ unsigned int fxs[256];
    __shared__ int nbase[256];
    __shared__ float ldsdinv[256];
    __shared__ int ss[256];
    int t = threadIdx.x, b = blockIdx.x;
    int beg = base[(size_t)b * nblk];
    int end = (b + 1 < nb) ? base[(size_t)(b + 1) * nblk] : e;
    if (t < 256) { cnt2[t] = 0; fxs[t] = 0u; }
    __syncthreads();
    for (int i = beg + t; i < end; i += 1024) {
        int ld = dlow[i];
        int r = atomicAdd(&cnt2[ld], 1);  // LDS atomic
        rank2[i] = (unsigned short)r;
        float w = __int_as_float(arr1[i].y);
        atomicAdd(&fxs[ld], (unsigned int)(w * FIX_SCALE + 0.5f));  // LDS, deterministic sum
    }
    __syncthreads();
    // exclusive scan of cnt2 -> nbase (all threads participate in syncs)
    if (t < 256) ss[t] = cnt2[t];
    __syncthreads();
    for (int off = 1; off < 256; off <<= 1) {
        int cur = 0, add = 0;
        if (t < 256) { cur = ss[t]; add = (t >= off) ? ss[t - off] : 0; }
        __syncthreads();
        if (t < 256) ss[t] = cur + add;
        __syncthreads();
    }
    if (t < 256) {
        nbase[t] = ss[t] - cnt2[t];
        int d = b * 256 + t;
        if (d < n) {
            float dv = rsqrtf(1.0f + (float)fxs[t] * (1.0f / FIX_SCALE));  // +1 self loop
            dinv[d] = dv;
            ldsdinv[t] = dv;
            row_ptr[d] = beg + nbase[t];
        }
    }
    __syncthreads();
    for (int i = beg + t; i < end; i += 1024) {
        int ld = dlow[i];
        int pos = beg + nbase[ld] + rank2[i];
        int2 a = arr1[i];
        float w = __int_as_float(a.y) * ldsdinv[ld];
        ep[pos] = make_int2(a.x, __float_as_int(w));
    }
}

// ---------- pass 5: ep.val *= dinv[src]; also writes row_ptr[N] ----------
__global__ void val_kernel(int2* __restrict__ ep, const float* __restrict__ dinv,
                           int* __restrict__ row_ptr, int n, int e) {
    int i = blockIdx.x * blockDim.x + threadIdx.x;
    if (i == 0) row_ptr[n] = e;
    if (i >= e) return;
    int2 a = ep[i];
    float w = __int_as_float(a.y) * dinv[a.x];
    ep[i] = make_int2(a.x, __float_as_int(w));
}

// ---------- GEMM: H[n x NOUT](fp16) = X[n x 128](fp32) @ W[128 x NOUT] ----------
// K split into two 64-phases -> LDS 49.4 KB (NOUT=128) -> 3 blocks/CU.
template <int NOUT>
__global__ __launch_bounds__(256) void gemm_kernel(const float* __restrict__ X,
                                                   const float* __restrict__ W,
                                                   __half* __restrict__ H, int n) {
    constexpr int CN = NOUT / 16;  // 8 (NOUT=128) or 4 (NOUT=64)
    __shared__ float Xs[64][68];
    __shared__ float Ws[64][NOUT];
    int t = threadIdx.x;
    int row0 = blockIdx.x * 64;
    int tx = t & 15, ty = t >> 4;
    int c0 = tx * CN;
    float acc[4][CN];
#pragma unroll
    for (int i = 0; i < 4; i++)
#pragma unroll
        for (int j = 0; j < CN; j++) acc[i][j] = 0.f;

    for (int kb = 0; kb < K_IN; kb += 64) {
        if (kb) __syncthreads();
        for (int i = t; i < 64 * NOUT / 4; i += 256) {
            int k = (i * 4) / NOUT, c = (i * 4) % NOUT;
            *(float4*)&Ws[k][c] = *(const float4*)(W + (size_t)(kb + k) * NOUT + c);
        }
        for (int i = t; i < 64 * 16; i += 256) {
            int r = i >> 4, k = (i & 15) << 2;
            int row = row0 + r;
            float4 x4 = make_float4(0.f, 0.f, 0.f, 0.f);
            if (row < n) x4 = *(const float4*)(X + (size_t)row * K_IN + kb + k);
            *(float4*)&Xs[r][k] = x4;
        }
        __syncthreads();

        for (int k = 0; k < 64; k += 4) {
            float4 xv[4];
#pragma unroll
            for (int i = 0; i < 4; i++) xv[i] = *(const float4*)&Xs[ty + 16 * i][k];
#pragma unroll
            for (int kk = 0; kk < 4; kk++) {
                float wv[CN];
#pragma unroll
                for (int j = 0; j < CN; j += 4) {
                    float4 w4 = *(const float4*)&Ws[k + kk][c0 + j];
                    wv[j] = w4.x; wv[j + 1] = w4.y; wv[j + 2] = w4.z; wv[j + 3] = w4.w;
                }
#pragma unroll
                for (int i = 0; i < 4; i++) {
                    float xs = (kk == 0) ? xv[i].x : (kk == 1) ? xv[i].y
                              : (kk == 2) ? xv[i].z : xv[i].w;
#pragma unroll
                    for (int j = 0; j < CN; j++) acc[i][j] += xs * wv[j];
                }
            }
        }
    }

#pragma unroll
    for (int i = 0; i < 4; i++) {
        int row = row0 + ty + 16 * i;
        if (row < n) {
            __half2 ph[CN / 2];
#pragma unroll
            for (int j = 0; j < CN / 2; j++)
                ph[j] = __floats2half2_rn(acc[i][2 * j], acc[i][2 * j + 1]);
            __half* dstp = H + (size_t)row * NOUT + c0;
            if (CN == 8)
                *reinterpret_cast<uint4*>(dstp) = *reinterpret_cast<uint4*>(ph);
            else
                *reinterpret_cast<uint2*>(dstp) = *reinterpret_cast<uint2*>(ph);
        }
    }
}

// ---------- aggregation: fp16 gathers, fp32 accumulate ----------
// one wave per node; UN=16 batch loop + ONE predicated tail batch.
template <int F, bool RELU>
__global__ __launch_bounds__(256) void agg_kernel(const __half* __restrict__ H,
                                                  const int* __restrict__ row_ptr,
                                                  const int2* __restrict__ ep,
                                                  const float* __restrict__ dinv,
                                                  const float* __restrict__ bias,
                                                  float* __restrict__ out, int n) {
    constexpr int UN = 16;
    int wid = threadIdx.x >> 6;
    int lane = threadIdx.x & 63;
    int node = blockIdx.x * 4 + wid;
    if (node >= n) return;

    int start = row_ptr[node], end = row_ptr[node + 1];
    float di = dinv[node];
    float sw = di * di;

    float a0, a1;
    if (F == 128) {
        float2 s2 = __half22float2(((const __half2*)(H + (size_t)node * 128))[lane]);
        a0 = s2.x * sw; a1 = s2.y * sw;
    } else {
        a0 = __half2float(H[(size_t)node * 64 + lane]) * sw; a1 = 0.f;
    }

    int len = end - start;
    int nf = len / UN;
    const int2* pp = ep + start;
    for (int b = 0; b < nf; b++, pp += UN) {
        int2 e[UN];
#pragma unroll
        for (int u = 0; u < UN; u++) e[u] = pp[u];
        __half2 v2[UN];
        __half v1[UN];
#pragma unroll
        for (int u = 0; u < UN; u++) {
            if (F == 128) v2[u] = ((const __half2*)(H + (size_t)e[u].x * 128))[lane];
            else          v1[u] = H[(size_t)e[u].x * 64 + lane];
        }
#pragma unroll
        for (int u = 0; u < UN; u++) {
            float w = __int_as_float(e[u].y);
            if (F == 128) {
                float2 f = __half22float2(v2[u]);
                a0 += w * f.x; a1 += w * f.y;
            } else {
                a0 += w * __half2float(v1[u]);
            }
        }
    }
    int base = start + nf * UN;
    if (base < end) {  // single predicated tail batch
        int2 e[UN];
#pragma unroll
        for (int u = 0; u < UN; u++) {
            int p = base + u;
            int q = (p < end) ? p : end - 1;
            int2 t2 = ep[q];
            if (p >= end) t2.y = 0;
            e[u] = t2;
        }
        __half2 v2[UN];
        __half v1[UN];
#pragma unroll
        for (int u = 0; u < UN; u++) {
            if (F == 128) v2[u] = ((const __half2*)(H + (size_t)e[u].x * 128))[lane];
            else          v1[u] = H[(size_t)e[u].x * 64 + lane];
        }
#pragma unroll
        for (int u = 0; u < UN; u++) {
            float w = __int_as_float(e[u].y);
            if (F == 128) {
                float2 f = __half22float2(v2[u]);
                a0 += w * f.x; a1 += w * f.y;
            } else {
                a0 += w * __half2float(v1[u]);
            }
        }
    }

    if (F == 128) {
        float o0 = a0 + bias[lane * 2];
        float o1 = a1 + bias[lane * 2 + 1];
        if (RELU) { o0 = fmaxf(o0, 0.f); o1 = fmaxf(o1, 0.f); }
        *(float2*)(out + (size_t)node * 128 + lane * 2) = make_float2(o0, o1);
    } else {
        float o = a0 + bias[lane];
        if (RELU) o = fmaxf(o, 0.f);
        out[(size_t)node * 64 + lane] = o;
    }
}

// ---------- launch ----------

extern "C" void kernel_launch(void* const* d_in, const int* in_sizes, int n_in,
                              void* d_out, int out_size, void* d_ws, size_t ws_size,
                              hipStream_t stream) {
    const float* x   = (const float*)d_in[0];
    const int*   ei  = (const int*)d_in[1];   // int32 (JAX x64 disabled)
    const float* ew  = (const float*)d_in[2];
    const float* W1  = (const float*)d_in[3];
    const float* b1  = (const float*)d_in[4];
    const float* W2  = (const float*)d_in[5];
    const float* b2  = (const float*)d_in[6];
    const float* W3  = (const float*)d_in[7];
    const float* b3  = (const float*)d_in[8];
    float* out = (float*)d_out;

    const int N = in_sizes[0] / K_IN;
    const int E = in_sizes[2];
    const int* src = ei;
    const int* dst = ei + E;

    const int NB   = (N + 255) >> 8;        // buckets (196 for N=50000), <=256
    const int NBLK = (E + CE - 1) / CE;     // partition blocks (391)
    const int M    = NB * NBLK;             // counts entries (76636)
    const int NBB  = (M + 255) / 256;       // scan blocks (300), <=1024

    char* w = (char*)d_ws;
    auto alloc = [&](size_t bytes) {
        void* p = (void*)w;
        w += (bytes + 255) & ~(size_t)255;
        return p;
    };
    int*            counts = (int*)alloc((size_t)M * 4);
    int*            base   = (int*)alloc((size_t)M * 4);
    int*            bsM    = (int*)alloc((size_t)NBB * 4);
    int*            boM    = (int*)alloc((size_t)NBB * 4);
    unsigned short* lrank  = (unsigned short*)alloc((size_t)E * 2);  // reused as rank2
    int2*           arr1   = (int2*)alloc((size_t)E * 8);
    unsigned char*  dlow   = (unsigned char*)alloc((size_t)E);
    float*          dinv   = (float*)alloc((size_t)N * 4);
    int*            row_ptr= (int*)alloc((size_t)(N + 1) * 4);
    int2*           ep     = (int2*)alloc((size_t)E * 8);
    __half*         bufH   = (__half*)alloc((size_t)N * 128 * 2);  // gemm out (fp16)
    float*          bufC   = (float*)alloc((size_t)N * 128 * 4);   // agg out (fp32)

    // ---- CSR build (no global atomics) ----
    part_count<<<NBLK, 1024, 0, stream>>>(dst, counts, lrank, NB, NBLK, E);
    reduce_kernel<<<NBB, 256, 0, stream>>>(counts, bsM, M);
    scanb1024<<<1, 1024, 0, stream>>>(bsM, boM, NBB);
    scanw_kernel<<<NBB, 256, 0, stream>>>(counts, boM, base, M);
    part_scatter<<<NBLK, 1024, 0, stream>>>(src, dst, ew, base, lrank, arr1, dlow, NBLK, E);
    bucket_csr<<<NB, 1024, 0, stream>>>(arr1, dlow, base, lrank, dinv, row_ptr, ep,
                                        NB, NBLK, N, E);
    val_kernel<<<(E + 255) / 256, 256, 0, stream>>>(ep, dinv, row_ptr, N, E);

    // ---- layers ----
    int gGemm = (N + 63) / 64;
    int gAgg  = (N + 3) / 4;

    gemm_kernel<128><<<gGemm, 256, 0, stream>>>(x, W1, bufH, N);
    agg_kernel<128, true><<<gAgg, 256, 0, stream>>>(bufH, row_ptr, ep, dinv, b1, bufC, N);
    gemm_kernel<128><<<gGemm, 256, 0, stream>>>(bufC, W2, bufH, N);
    agg_kernel<128, true><<<gAgg, 256, 0, stream>>>(bufH, row_ptr, ep, dinv, b2, bufC, N);
    gemm_kernel<64><<<gGemm, 256, 0, stream>>>(bufC, W3, bufH, N);
    agg_kernel<64, false><<<gAgg, 256, 0, stream>>>(bufH, row_ptr, ep, dinv, b3, out, N);
}

// Round 8
// 380.322 us; speedup vs baseline: 2.8033x; 1.0964x over previous
//
#include <hip/hip_runtime.h>
#include <hip/hip_bf16.h>
#include <hip/hip_fp16.h>

// GCN 3-layer. R8: MFMA GEMMs. fp32 VALU gemms (est 30-45us each, MfmaUtil=0)
// -> mfma_f32_16x16x32_f16: W pre-transposed to fp16 [n][k] once per layer,
// X staged fp16 in LDS (136-half padded rows = free 2-way bank aliasing),
// 4 waves x (4 row-tiles x CTW col-tiles), fp32 accum. agg now emits fp16
// (halves its write traffic + feeds gemm2/3 directly). Build (R7 sort-based,
// zero global atomics) and agg gather structure unchanged.

#define K_IN 128              // all layers have in_features == 128
#define FIX_SCALE 8388608.0f  // 2^23 fixed point for ew sums
#define CE 4096               // edges per partition block (1024 thr x 4)

typedef _Float16 f16x8 __attribute__((ext_vector_type(8)));
typedef float f32x4 __attribute__((ext_vector_type(4)));

// ---------- pass 1: per-block bucket histogram + local rank ----------
__global__ __launch_bounds__(1024) void part_count(const int* __restrict__ dst,
                                                   int* __restrict__ counts,
                                                   unsigned short* __restrict__ lrank,
                                                   int nb, int nblk, int e) {
    __shared__ int c[256];  // nb <= 256
    int t = threadIdx.x, blk = blockIdx.x;
    for (int i = t; i < nb; i += 1024) c[i] = 0;
    __syncthreads();
    int b0 = blk * CE;
#pragma unroll
    for (int j = 0; j < 4; j++) {
        int i = b0 + j * 1024 + t;
        if (i < e) {
            int b = dst[i] >> 8;
            int r = atomicAdd(&c[b], 1);  // LDS atomic
            lrank[i] = (unsigned short)r;
        }
    }
    __syncthreads();
    for (int i = t; i < nb; i += 1024) counts[(size_t)i * nblk + blk] = c[i];
}

// ---------- pass 2: parallel exclusive scan over counts[nb*nblk] ----------
__global__ __launch_bounds__(256) void reduce_kernel(const int* __restrict__ v,
                                                     int* __restrict__ bs, int m) {
    __shared__ int s[256];
    int t = threadIdx.x, i = blockIdx.x * 256 + t;
    s[t] = (i < m) ? v[i] : 0;
    __syncthreads();
    for (int off = 128; off > 0; off >>= 1) {
        if (t < off) s[t] += s[t + off];
        __syncthreads();
    }
    if (t == 0) bs[blockIdx.x] = s[0];
}

__global__ __launch_bounds__(1024) void scanb1024(const int* __restrict__ bs,
                                                  int* __restrict__ bo, int nbb) {
    __shared__ int s[1024];
    int t = threadIdx.x;
    s[t] = (t < nbb) ? bs[t] : 0;
    __syncthreads();
    for (int off = 1; off < 1024; off <<= 1) {
        int cur = s[t];
        int add = (t >= off) ? s[t - off] : 0;
        __syncthreads();
        s[t] = cur + add;
        __syncthreads();
    }
    if (t < nbb) bo[t] = (t == 0) ? 0 : s[t - 1];
}

__global__ __launch_bounds__(256) void scanw_kernel(const int* __restrict__ v,
                                                    const int* __restrict__ bo,
                                                    int* __restrict__ outp, int m) {
    __shared__ int s[256];
    int t = threadIdx.x, i = blockIdx.x * 256 + t;
    int c = (i < m) ? v[i] : 0;
    s[t] = c;
    __syncthreads();
    for (int off = 1; off < 256; off <<= 1) {
        int cur = s[t];
        int add = (t >= off) ? s[t - off] : 0;
        __syncthreads();
        s[t] = cur + add;
        __syncthreads();
    }
    if (i < m) outp[i] = bo[blockIdx.x] + (s[t] - c);  // exclusive
}

// ---------- pass 3: scatter into bucket-sorted order ----------
__global__ __launch_bounds__(1024) void part_scatter(const int* __restrict__ src,
                                                     const int* __restrict__ dst,
                                                     const float* __restrict__ ew,
                                                     const int* __restrict__ base,
                                                     const unsigned short* __restrict__ lrank,
                                                     int2* __restrict__ arr1,
                                                     unsigned char* __restrict__ dlow,
                                                     int nblk, int e) {
    int t = threadIdx.x, blk = blockIdx.x;
    int b0 = blk * CE;
#pragma unroll
    for (int j = 0; j < 4; j++) {
        int i = b0 + j * 1024 + t;
        if (i < e) {
            int d = dst[i];
            int b = d >> 8;
            int pos = base[(size_t)b * nblk + blk] + lrank[i];
            arr1[pos] = make_int2(src[i], __float_as_int(ew[i]));
            dlow[pos] = (unsigned char)(d & 255);
        }
    }
}

// ---------- pass 4: per-bucket CSR finalize ----------
__global__ __launch_bounds__(1024) void bucket_csr(const int2* __restrict__ arr1,
                                                   const unsigned char* __restrict__ dlow,
                                                   const int* __restrict__ base,
                                                   unsigned short* __restrict__ rank2,
                                                   float* __restrict__ dinv,
                                                   int* __restrict__ row_ptr,
                                                   int2* __restrict__ ep,
                                                   int nb, int nblk, int n, int e) {
    __shared__ int cnt2[256];
    __shared__ unsigned int fxs[256];
    __shared__ int nbase[256];
    __shared__ float ldsdinv[256];
    __shared__ int ss[256];
    int t = threadIdx.x, b = blockIdx.x;
    int beg = base[(size_t)b * nblk];
    int end = (b + 1 < nb) ? base[(size_t)(b + 1) * nblk] : e;
    if (t < 256) { cnt2[t] = 0; fxs[t] = 0u; }
    __syncthreads();
    for (int i = beg + t; i < end; i += 1024) {
        int ld = dlow[i];
        int r = atomicAdd(&cnt2[ld], 1);  // LDS atomic
        rank2[i] = (unsigned short)r;
        float w = __int_as_float(arr1[i].y);
        atomicAdd(&fxs[ld], (unsigned int)(w * FIX_SCALE + 0.5f));  // LDS, deterministic
    }
    __syncthreads();
    if (t < 256) ss[t] = cnt2[t];
    __syncthreads();
    for (int off = 1; off < 256; off <<= 1) {
        int cur = 0, add = 0;
        if (t < 256) { cur = ss[t]; add = (t >= off) ? ss[t - off] : 0; }
        __syncthreads();
        if (t < 256) ss[t] = cur + add;
        __syncthreads();
    }
    if (t < 256) {
        nbase[t] = ss[t] - cnt2[t];
        int d = b * 256 + t;
        if (d < n) {
            float dv = rsqrtf(1.0f + (float)fxs[t] * (1.0f / FIX_SCALE));  // +1 self loop
            dinv[d] = dv;
            ldsdinv[t] = dv;
            row_ptr[d] = beg + nbase[t];
        }
    }
    __syncthreads();
    for (int i = beg + t; i < end; i += 1024) {
        int ld = dlow[i];
        int pos = beg + nbase[ld] + rank2[i];
        int2 a = arr1[i];
        float w = __int_as_float(a.y) * ldsdinv[ld];
        ep[pos] = make_int2(a.x, __float_as_int(w));
    }
}

// ---------- pass 5: ep.val *= dinv[src]; also writes row_ptr[N] ----------
__global__ void val_kernel(int2* __restrict__ ep, const float* __restrict__ dinv,
                           int* __restrict__ row_ptr, int n, int e) {
    int i = blockIdx.x * blockDim.x + threadIdx.x;
    if (i == 0) row_ptr[n] = e;
    if (i >= e) return;
    int2 a = ep[i];
    float w = __int_as_float(a.y) * dinv[a.x];
    ep[i] = make_int2(a.x, __float_as_int(w));
}

// ---------- W prep: Wt[n][k] fp16 = W[k][n] fp32 ----------
__global__ void wt_prep(const float* __restrict__ W, _Float16* __restrict__ Wt, int nout) {
    int i = blockIdx.x * blockDim.x + threadIdx.x;
    if (i >= nout * K_IN) return;
    int k = i / nout, nn = i - k * nout;  // coalesced read of W
    Wt[(size_t)nn * K_IN + k] = (_Float16)W[i];
}

// ---------- MFMA GEMM: H[n x NOUT](fp16) = X[n x 128] @ W ----------
// block = 64 rows x NOUT cols, 4 waves; wave w: 4 row-tiles x CTW col-tiles.
// A-frag: A[m=lane&15][k=kt*32+(lane>>4)*8+j]; B-frag from Wt[n][k] likewise;
// D: col=lane&15, row=(lane>>4)*4+reg.
template <int NOUT, bool XF16>
__global__ __launch_bounds__(256) void mfma_gemm(const void* __restrict__ Xv,
                                                 const _Float16* __restrict__ Wt,
                                                 _Float16* __restrict__ H, int n) {
    constexpr int CTW = NOUT / 64;  // col-tiles per wave: 2 (NOUT=128) / 1 (64)
    __shared__ _Float16 Xs[64][136];   // +8 pad: row stride 272B -> 2-way banks
    __shared__ _Float16 Ws[NOUT][136];
    int t = threadIdx.x;
    int row0 = blockIdx.x * 64;

    // stage Wt (fp16, contiguous) -> Ws
    for (int i = t * 8; i < NOUT * K_IN; i += 2048) {
        int nn = i >> 7, k = i & 127;
        *(uint4*)&Ws[nn][k] = *(const uint4*)&Wt[i];
    }
    // stage X -> Xs (fp16)
    if (XF16) {
        const _Float16* X = (const _Float16*)Xv;
        for (int i = t * 8; i < 64 * K_IN; i += 2048) {
            int r = i >> 7, k = i & 127;
            int row = row0 + r;
            uint4 v = make_uint4(0u, 0u, 0u, 0u);
            if (row < n) v = *(const uint4*)(X + (size_t)row * K_IN + k);
            *(uint4*)&Xs[r][k] = v;
        }
    } else {
        const float* X = (const float*)Xv;
        for (int i = t * 4; i < 64 * K_IN; i += 1024) {
            int r = i >> 7, k = i & 127;
            int row = row0 + r;
            float4 x4 = make_float4(0.f, 0.f, 0.f, 0.f);
            if (row < n) x4 = *(const float4*)(X + (size_t)row * K_IN + k);
            union { _Float16 h[4]; uint2 u; } uu;
            uu.h[0] = (_Float16)x4.x; uu.h[1] = (_Float16)x4.y;
            uu.h[2] = (_Float16)x4.z; uu.h[3] = (_Float16)x4.w;
            *(uint2*)&Xs[r][k] = uu.u;
        }
    }
    __syncthreads();

    int lane = t & 63, w = t >> 6;
    int m = lane & 15, g = lane >> 4;  // g: k-group / D-row group
    f32x4 acc[4][CTW];
#pragma unroll
    for (int mt = 0; mt < 4; mt++)
#pragma unroll
        for (int ct = 0; ct < CTW; ct++) acc[mt][ct] = (f32x4){0.f, 0.f, 0.f, 0.f};

#pragma unroll
    for (int kt = 0; kt < 4; kt++) {
        int kb = kt * 32 + g * 8;
        f16x8 a[4];
#pragma unroll
        for (int mt = 0; mt < 4; mt++) a[mt] = *(const f16x8*)&Xs[mt * 16 + m][kb];
#pragma unroll
        for (int ct = 0; ct < CTW; ct++) {
            int nn = w * (16 * CTW) + ct * 16 + m;
            f16x8 b = *(const f16x8*)&Ws[nn][kb];
#pragma unroll
            for (int mt = 0; mt < 4; mt++)
                acc[mt][ct] = __builtin_amdgcn_mfma_f32_16x16x32_f16(a[mt], b, acc[mt][ct], 0, 0, 0);
        }
    }

#pragma unroll
    for (int mt = 0; mt < 4; mt++) {
#pragma unroll
        for (int r = 0; r < 4; r++) {
            int row = row0 + mt * 16 + g * 4 + r;
            if (row < n) {
#pragma unroll
                for (int ct = 0; ct < CTW; ct++)
                    H[(size_t)row * NOUT + w * (16 * CTW) + ct * 16 + m] =
                        (_Float16)acc[mt][ct][r];
            }
        }
    }
}

// ---------- aggregation: fp16 gathers, fp32 accumulate ----------
// one wave per node; UN=16 batch loop + ONE predicated tail batch.
// OF16: emit fp16 (feeds next gemm); else fp32 (final output).
template <int F, bool RELU, bool OF16>
__global__ __launch_bounds__(256) void agg_kernel(const __half* __restrict__ H,
                                                  const int* __restrict__ row_ptr,
                                                  const int2* __restrict__ ep,
                                                  const float* __restrict__ dinv,
                                                  const float* __restrict__ bias,
                                                  void* __restrict__ outv, int n) {
    constexpr int UN = 16;
    int wid = threadIdx.x >> 6;
    int lane = threadIdx.x & 63;
    int node = blockIdx.x * 4 + wid;
    if (node >= n) return;

    int start = row_ptr[node], end = row_ptr[node + 1];
    float di = dinv[node];
    float sw = di * di;

    float a0, a1;
    if (F == 128) {
        float2 s2 = __half22float2(((const __half2*)(H + (size_t)node * 128))[lane]);
        a0 = s2.x * sw; a1 = s2.y * sw;
    } else {
        a0 = __half2float(H[(size_t)node * 64 + lane]) * sw; a1 = 0.f;
    }

    int len = end - start;
    int nf = len / UN;
    const int2* pp = ep + start;
    for (int b = 0; b < nf; b++, pp += UN) {
        int2 e[UN];
#pragma unroll
        for (int u = 0; u < UN; u++) e[u] = pp[u];
        __half2 v2[UN];
        __half v1[UN];
#pragma unroll
        for (int u = 0; u < UN; u++) {
            if (F == 128) v2[u] = ((const __half2*)(H + (size_t)e[u].x * 128))[lane];
            else          v1[u] = H[(size_t)e[u].x * 64 + lane];
        }
#pragma unroll
        for (int u = 0; u < UN; u++) {
            float w = __int_as_float(e[u].y);
            if (F == 128) {
                float2 f = __half22float2(v2[u]);
                a0 += w * f.x; a1 += w * f.y;
            } else {
                a0 += w * __half2float(v1[u]);
            }
        }
    }
    int base = start + nf * UN;
    if (base < end) {  // single predicated tail batch
        int2 e[UN];
#pragma unroll
        for (int u = 0; u < UN; u++) {
            int p = base + u;
            int q = (p < end) ? p : end - 1;
            int2 t2 = ep[q];
            if (p >= end) t2.y = 0;
            e[u] = t2;
        }
        __half2 v2[UN];
        __half v1[UN];
#pragma unroll
        for (int u = 0; u < UN; u++) {
            if (F == 128) v2[u] = ((const __half2*)(H + (size_t)e[u].x * 128))[lane];
            else          v1[u] = H[(size_t)e[u].x * 64 + lane];
        }
#pragma unroll
        for (int u = 0; u < UN; u++) {
            float w = __int_as_float(e[u].y);
            if (F == 128) {
                float2 f = __half22float2(v2[u]);
                a0 += w * f.x; a1 += w * f.y;
            } else {
                a0 += w * __half2float(v1[u]);
            }
        }
    }

    if (F == 128) {
        float o0 = a0 + bias[lane * 2];
        float o1 = a1 + bias[lane * 2 + 1];
        if (RELU) { o0 = fmaxf(o0, 0.f); o1 = fmaxf(o1, 0.f); }
        if (OF16) {
            ((__half2*)outv)[(size_t)node * 64 + lane] = __floats2half2_rn(o0, o1);
        } else {
            *(float2*)((float*)outv + (size_t)node * 128 + lane * 2) = make_float2(o0, o1);
        }
    } else {
        float o = a0 + bias[lane];
        if (RELU) o = fmaxf(o, 0.f);
        if (OF16) ((__half*)outv)[(size_t)node * 64 + lane] = __float2half(o);
        else      ((float*)outv)[(size_t)node * 64 + lane] = o;
    }
}

// ---------- launch ----------

extern "C" void kernel_launch(void* const* d_in, const int* in_sizes, int n_in,
                              void* d_out, int out_size, void* d_ws, size_t ws_size,
                              hipStream_t stream) {
    const float* x   = (const float*)d_in[0];
    const int*   ei  = (const int*)d_in[1];   // int32 (JAX x64 disabled)
    const float* ew  = (const float*)d_in[2];
    const float* W1  = (const float*)d_in[3];
    const float* b1  = (const float*)d_in[4];
    const float* W2  = (const float*)d_in[5];
    const float* b2  = (const float*)d_in[6];
    const float* W3  = (const float*)d_in[7];
    const float* b3  = (const float*)d_in[8];
    float* out = (float*)d_out;

    const int N = in_sizes[0] / K_IN;
    const int E = in_sizes[2];
    const int* src = ei;
    const int* dst = ei + E;

    const int NB   = (N + 255) >> 8;     // buckets, <=256
    const int NBLK = (E + CE - 1) / CE;  // partition blocks
    const int M    = NB * NBLK;
    const int NBB  = (M + 255) / 256;

    char* w = (char*)d_ws;
    auto alloc = [&](size_t bytes) {
        void* p = (void*)w;
        w += (bytes + 255) & ~(size_t)255;
        return p;
    };
    int*            counts = (int*)alloc((size_t)M * 4);
    int*            base   = (int*)alloc((size_t)M * 4);
    int*            bsM    = (int*)alloc((size_t)NBB * 4);
    int*            boM    = (int*)alloc((size_t)NBB * 4);
    unsigned short* lrank  = (unsigned short*)alloc((size_t)E * 2);  // reused as rank2
    int2*           arr1   = (int2*)alloc((size_t)E * 8);
    unsigned char*  dlow   = (unsigned char*)alloc((size_t)E);
    float*          dinv   = (float*)alloc((size_t)N * 4);
    int*            row_ptr= (int*)alloc((size_t)(N + 1) * 4);
    int2*           ep     = (int2*)alloc((size_t)E * 8);
    _Float16*       Wt1    = (_Float16*)alloc(128 * 128 * 2);
    _Float16*       Wt2    = (_Float16*)alloc(128 * 128 * 2);
    _Float16*       Wt3    = (_Float16*)alloc(64 * 128 * 2);
    _Float16*       bufH   = (_Float16*)alloc((size_t)N * 128 * 2);  // gemm out
    _Float16*       bufX   = (_Float16*)alloc((size_t)N * 128 * 2);  // agg out (fp16)

    // ---- CSR build (no global atomics) ----
    part_count<<<NBLK, 1024, 0, stream>>>(dst, counts, lrank, NB, NBLK, E);
    reduce_kernel<<<NBB, 256, 0, stream>>>(counts, bsM, M);
    scanb1024<<<1, 1024, 0, stream>>>(bsM, boM, NBB);
    scanw_kernel<<<NBB, 256, 0, stream>>>(counts, boM, base, M);
    part_scatter<<<NBLK, 1024, 0, stream>>>(src, dst, ew, base, lrank, arr1, dlow, NBLK, E);
    bucket_csr<<<NB, 1024, 0, stream>>>(arr1, dlow, base, lrank, dinv, row_ptr, ep,
                                        NB, NBLK, N, E);
    val_kernel<<<(E + 255) / 256, 256, 0, stream>>>(ep, dinv, row_ptr, N, E);

    // ---- W prep (fp16 transposed) ----
    wt_prep<<<(128 * 128 + 255) / 256, 256, 0, stream>>>(W1, Wt1, 128);
    wt_prep<<<(128 * 128 + 255) / 256, 256, 0, stream>>>(W2, Wt2, 128);
    wt_prep<<<(64 * 128 + 255) / 256, 256, 0, stream>>>(W3, Wt3, 64);

    // ---- layers ----
    int gGemm = (N + 63) / 64;
    int gAgg  = (N + 3) / 4;

    mfma_gemm<128, false><<<gGemm, 256, 0, stream>>>(x, Wt1, bufH, N);
    agg_kernel<128, true, true><<<gAgg, 256, 0, stream>>>((const __half*)bufH, row_ptr, ep,
                                                          dinv, b1, bufX, N);
    mfma_gemm<128, true><<<gGemm, 256, 0, stream>>>(bufX, Wt2, bufH, N);
    agg_kernel<128, true, true><<<gAgg, 256, 0, stream>>>((const __half*)bufH, row_ptr, ep,
                                                          dinv, b2, bufX, N);
    mfma_gemm<64, true><<<gGemm, 256, 0, stream>>>(bufX, Wt3, bufH, N);
    agg_kernel<64, false, false><<<gAgg, 256, 0, stream>>>((const __half*)bufH, row_ptr, ep,
                                                           dinv, b3, out, N);
}

// Round 9
// 316.612 us; speedup vs baseline: 3.3673x; 1.2012x over previous
//
#include <hip/hip_runtime.h>
#include <hip/hip_bf16.h>
#include <hip/hip_fp16.h>

// GCN 3-layer. R9: agg de-VALU-ification. R8 agg<128>: 67us, VALUBusy 47% —
// half the VALU was 64-bit gather address math (mul64/carry per edge-lane) +
// per-lane ep addressing. Now: (1) ep.x stores BYTE offset (src<<8) -> gather
// addr = sgpr H base + (off + lane*4), one v_add, saddr global_load;
// (2) start/end readfirstlane'd -> batch bookkeeping + 16 ep record loads go
// scalar (s_load), freeing VALU + vector-mem pipe for gathers. (3) wt_prep
// fused to 1 launch. Build (R7 sort, no global atomics) + MFMA gemms (R8)
// unchanged.

#define K_IN 128              // all layers have in_features == 128
#define FIX_SCALE 8388608.0f  // 2^23 fixed point for ew sums
#define CE 4096               // edges per partition block (1024 thr x 4)

typedef _Float16 f16x8 __attribute__((ext_vector_type(8)));
typedef float f32x4 __attribute__((ext_vector_type(4)));

// ---------- pass 1: per-block bucket histogram + local rank ----------
__global__ __launch_bounds__(1024) void part_count(const int* __restrict__ dst,
                                                   int* __restrict__ counts,
                                                   unsigned short* __restrict__ lrank,
                                                   int nb, int nblk, int e) {
    __shared__ int c[256];  // nb <= 256
    int t = threadIdx.x, blk = blockIdx.x;
    for (int i = t; i < nb; i += 1024) c[i] = 0;
    __syncthreads();
    int b0 = blk * CE;
#pragma unroll
    for (int j = 0; j < 4; j++) {
        int i = b0 + j * 1024 + t;
        if (i < e) {
            int b = dst[i] >> 8;
            int r = atomicAdd(&c[b], 1);  // LDS atomic
            lrank[i] = (unsigned short)r;
        }
    }
    __syncthreads();
    for (int i = t; i < nb; i += 1024) counts[(size_t)i * nblk + blk] = c[i];
}

// ---------- pass 2: parallel exclusive scan over counts[nb*nblk] ----------
__global__ __launch_bounds__(256) void reduce_kernel(const int* __restrict__ v,
                                                     int* __restrict__ bs, int m) {
    __shared__ int s[256];
    int t = threadIdx.x, i = blockIdx.x * 256 + t;
    s[t] = (i < m) ? v[i] : 0;
    __syncthreads();
    for (int off = 128; off > 0; off >>= 1) {
        if (t < off) s[t] += s[t + off];
        __syncthreads();
    }
    if (t == 0) bs[blockIdx.x] = s[0];
}

__global__ __launch_bounds__(1024) void scanb1024(const int* __restrict__ bs,
                                                  int* __restrict__ bo, int nbb) {
    __shared__ int s[1024];
    int t = threadIdx.x;
    s[t] = (t < nbb) ? bs[t] : 0;
    __syncthreads();
    for (int off = 1; off < 1024; off <<= 1) {
        int cur = s[t];
        int add = (t >= off) ? s[t - off] : 0;
        __syncthreads();
        s[t] = cur + add;
        __syncthreads();
    }
    if (t < nbb) bo[t] = (t == 0) ? 0 : s[t - 1];
}

__global__ __launch_bounds__(256) void scanw_kernel(const int* __restrict__ v,
                                                    const int* __restrict__ bo,
                                                    int* __restrict__ outp, int m) {
    __shared__ int s[256];
    int t = threadIdx.x, i = blockIdx.x * 256 + t;
    int c = (i < m) ? v[i] : 0;
    s[t] = c;
    __syncthreads();
    for (int off = 1; off < 256; off <<= 1) {
        int cur = s[t];
        int add = (t >= off) ? s[t - off] : 0;
        __syncthreads();
        s[t] = cur + add;
        __syncthreads();
    }
    if (i < m) outp[i] = bo[blockIdx.x] + (s[t] - c);  // exclusive
}

// ---------- pass 3: scatter into bucket-sorted order ----------
__global__ __launch_bounds__(1024) void part_scatter(const int* __restrict__ src,
                                                     const int* __restrict__ dst,
                                                     const float* __restrict__ ew,
                                                     const int* __restrict__ base,
                                                     const unsigned short* __restrict__ lrank,
                                                     int2* __restrict__ arr1,
                                                     unsigned char* __restrict__ dlow,
                                                     int nblk, int e) {
    int t = threadIdx.x, blk = blockIdx.x;
    int b0 = blk * CE;
#pragma unroll
    for (int j = 0; j < 4; j++) {
        int i = b0 + j * 1024 + t;
        if (i < e) {
            int d = dst[i];
            int b = d >> 8;
            int pos = base[(size_t)b * nblk + blk] + lrank[i];
            arr1[pos] = make_int2(src[i], __float_as_int(ew[i]));
            dlow[pos] = (unsigned char)(d & 255);
        }
    }
}

// ---------- pass 4: per-bucket CSR finalize ----------
__global__ __launch_bounds__(1024) void bucket_csr(const int2* __restrict__ arr1,
                                                   const unsigned char* __restrict__ dlow,
                                                   const int* __restrict__ base,
                                                   unsigned short* __restrict__ rank2,
                                                   float* __restrict__ dinv,
                                                   int* __restrict__ row_ptr,
                                                   int2* __restrict__ ep,
                                                   int nb, int nblk, int n, int e) {
    __shared__ int cnt2[256];
    __shared__ unsigned int fxs[256];
    __shared__ int nbase[256];
    __shared__ float ldsdinv[256];
    __shared__ int ss[256];
    int t = threadIdx.x, b = blockIdx.x;
    int beg = base[(size_t)b * nblk];
    int end = (b + 1 < nb) ? base[(size_t)(b + 1) * nblk] : e;
    if (t < 256) { cnt2[t] = 0; fxs[t] = 0u; }
    __syncthreads();
    for (int i = beg + t; i < end; i += 1024) {
        int ld = dlow[i];
        int r = atomicAdd(&cnt2[ld], 1);  // LDS atomic
        rank2[i] = (unsigned short)r;
        float w = __int_as_float(arr1[i].y);
        atomicAdd(&fxs[ld], (unsigned int)(w * FIX_SCALE + 0.5f));  // LDS, deterministic
    }
    __syncthreads();
    if (t < 256) ss[t] = cnt2[t];
    __syncthreads();
    for (int off = 1; off < 256; off <<= 1) {
        int cur = 0, add = 0;
        if (t < 256) { cur = ss[t]; add = (t >= off) ? ss[t - off] : 0; }
        __syncthreads();
        if (t < 256) ss[t] = cur + add;
        __syncthreads();
    }
    if (t < 256) {
        nbase[t] = ss[t] - cnt2[t];
        int d = b * 256 + t;
        if (d < n) {
            float dv = rsqrtf(1.0f + (float)fxs[t] * (1.0f / FIX_SCALE));  // +1 self loop
            dinv[d] = dv;
            ldsdinv[t] = dv;
            row_ptr[d] = beg + nbase[t];
        }
    }
    __syncthreads();
    for (int i = beg + t; i < end; i += 1024) {
        int ld = dlow[i];
        int pos = beg + nbase[ld] + rank2[i];
        int2 a = arr1[i];
        float w = __int_as_float(a.y) * ldsdinv[ld];
        ep[pos] = make_int2(a.x, __float_as_int(w));
    }
}

// ---------- pass 5: ep = (byte offset src*256, w*dinv[src]); row_ptr[N]=E ----------
__global__ void val_kernel(int2* __restrict__ ep, const float* __restrict__ dinv,
                           int* __restrict__ row_ptr, int n, int e) {
    int i = blockIdx.x * blockDim.x + threadIdx.x;
    if (i == 0) row_ptr[n] = e;
    if (i >= e) return;
    int2 a = ep[i];
    float w = __int_as_float(a.y) * dinv[a.x];
    ep[i] = make_int2(a.x << 8, __float_as_int(w));  // src*256 B (fp16 row, F=128)
}

// ---------- W prep (all 3 layers, one launch): Wt[n][k] fp16 = W[k][n] fp32 ----------
__global__ void wt_prep_all(const float* __restrict__ W1, const float* __restrict__ W2,
                            const float* __restrict__ W3, _Float16* __restrict__ Wt1,
                            _Float16* __restrict__ Wt2, _Float16* __restrict__ Wt3) {
    int i = blockIdx.x * 256 + threadIdx.x;
    if (i < 128 * 128) {
        int k = i >> 7, nn = i & 127;
        Wt1[(size_t)nn * 128 + k] = (_Float16)W1[i];
        return;
    }
    int j = i - 128 * 128;
    if (j < 128 * 128) {
        int k = j >> 7, nn = j & 127;
        Wt2[(size_t)nn * 128 + k] = (_Float16)W2[j];
        return;
    }
    int l = j - 128 * 128;
    if (l < 64 * 128) {
        int k = l >> 6, nn = l & 63;
        Wt3[(size_t)nn * 128 + k] = (_Float16)W3[l];
    }
}

// ---------- MFMA GEMM: H[n x NOUT](fp16) = X[n x 128] @ W ----------
template <int NOUT, bool XF16>
__global__ __launch_bounds__(256) void mfma_gemm(const void* __restrict__ Xv,
                                                 const _Float16* __restrict__ Wt,
                                                 _Float16* __restrict__ H, int n) {
    constexpr int CTW = NOUT / 64;  // col-tiles per wave: 2 (NOUT=128) / 1 (64)
    __shared__ _Float16 Xs[64][136];   // +8 pad: row stride 272B -> 2-way banks
    __shared__ _Float16 Ws[NOUT][136];
    int t = threadIdx.x;
    int row0 = blockIdx.x * 64;

    for (int i = t * 8; i < NOUT * K_IN; i += 2048) {
        int nn = i >> 7, k = i & 127;
        *(uint4*)&Ws[nn][k] = *(const uint4*)&Wt[i];
    }
    if (XF16) {
        const _Float16* X = (const _Float16*)Xv;
        for (int i = t * 8; i < 64 * K_IN; i += 2048) {
            int r = i >> 7, k = i & 127;
            int row = row0 + r;
            uint4 v = make_uint4(0u, 0u, 0u, 0u);
            if (row < n) v = *(const uint4*)(X + (size_t)row * K_IN + k);
            *(uint4*)&Xs[r][k] = v;
        }
    } else {
        const float* X = (const float*)Xv;
        for (int i = t * 4; i < 64 * K_IN; i += 1024) {
            int r = i >> 7, k = i & 127;
            int row = row0 + r;
            float4 x4 = make_float4(0.f, 0.f, 0.f, 0.f);
            if (row < n) x4 = *(const float4*)(X + (size_t)row * K_IN + k);
            union { _Float16 h[4]; uint2 u; } uu;
            uu.h[0] = (_Float16)x4.x; uu.h[1] = (_Float16)x4.y;
            uu.h[2] = (_Float16)x4.z; uu.h[3] = (_Float16)x4.w;
            *(uint2*)&Xs[r][k] = uu.u;
        }
    }
    __syncthreads();

    int lane = t & 63, w = t >> 6;
    int m = lane & 15, g = lane >> 4;
    f32x4 acc[4][CTW];
#pragma unroll
    for (int mt = 0; mt < 4; mt++)
#pragma unroll
        for (int ct = 0; ct < CTW; ct++) acc[mt][ct] = (f32x4){0.f, 0.f, 0.f, 0.f};

#pragma unroll
    for (int kt = 0; kt < 4; kt++) {
        int kb = kt * 32 + g * 8;
        f16x8 a[4];
#pragma unroll
        for (int mt = 0; mt < 4; mt++) a[mt] = *(const f16x8*)&Xs[mt * 16 + m][kb];
#pragma unroll
        for (int ct = 0; ct < CTW; ct++) {
            int nn = w * (16 * CTW) + ct * 16 + m;
            f16x8 b = *(const f16x8*)&Ws[nn][kb];
#pragma unroll
            for (int mt = 0; mt < 4; mt++)
                acc[mt][ct] = __builtin_amdgcn_mfma_f32_16x16x32_f16(a[mt], b, acc[mt][ct], 0, 0, 0);
        }
    }

#pragma unroll
    for (int mt = 0; mt < 4; mt++) {
#pragma unroll
        for (int r = 0; r < 4; r++) {
            int row = row0 + mt * 16 + g * 4 + r;
            if (row < n) {
#pragma unroll
                for (int ct = 0; ct < CTW; ct++)
                    H[(size_t)row * NOUT + w * (16 * CTW) + ct * 16 + m] =
                        (_Float16)acc[mt][ct][r];
            }
        }
    }
}

// ---------- aggregation: scalar ep loads, 1-VALU-add gathers, fp32 accum ----------
// one wave per node; start/end readfirstlane'd -> batch bookkeeping + ep record
// loads are SALU/s_load; gather addr = H(sgpr) + (byte_off + lane*elt).
template <int F, bool RELU, bool OF16>
__global__ __launch_bounds__(256) void agg_kernel(const __half* __restrict__ H,
                                                  const int* __restrict__ row_ptr,
                                                  const int2* __restrict__ ep,
                                                  const float* __restrict__ dinv,
                                                  const float* __restrict__ bias,
                                                  void* __restrict__ outv, int n) {
    constexpr int UN = 16;
    int wid = threadIdx.x >> 6;
    int lane = threadIdx.x & 63;
    int node = blockIdx.x * 4 + wid;
    if (node >= n) return;

    int start = __builtin_amdgcn_readfirstlane(row_ptr[node]);
    int end   = __builtin_amdgcn_readfirstlane(row_ptr[node + 1]);
    float di = dinv[node];
    float sw = di * di;

    const unsigned lb = (unsigned)lane * (F == 128 ? 4u : 2u);  // lane byte offset

    float a0, a1;
    if (F == 128) {
        float2 s2 = __half22float2(((const __half2*)(H + (size_t)node * 128))[lane]);
        a0 = s2.x * sw; a1 = s2.y * sw;
    } else {
        a0 = __half2float(H[(size_t)node * 64 + lane]) * sw; a1 = 0.f;
    }

    int len = end - start;
    int nf = len / UN;
    for (int b = 0; b < nf; b++) {
        int p0 = start + b * UN;
        int2 e[UN];
#pragma unroll
        for (int u = 0; u < UN; u++) e[u] = ep[p0 + u];  // uniform addr -> s_load
        __half2 v2[UN];
        __half v1[UN];
#pragma unroll
        for (int u = 0; u < UN; u++) {
            unsigned off = (unsigned)e[u].x;
            if (F == 64) off >>= 1;
            if (F == 128) v2[u] = *(const __half2*)((const char*)H + (off + lb));
            else          v1[u] = *(const __half*)((const char*)H + (off + lb));
        }
#pragma unroll
        for (int u = 0; u < UN; u++) {
            float w = __int_as_float(e[u].y);
            if (F == 128) {
                float2 f = __half22float2(v2[u]);
                a0 += w * f.x; a1 += w * f.y;
            } else {
                a0 += w * __half2float(v1[u]);
            }
        }
    }
    int base = start + nf * UN;
    if (base < end) {  // single predicated tail batch (uniform predicates)
        int2 e[UN];
#pragma unroll
        for (int u = 0; u < UN; u++) {
            int p = base + u;
            int q = (p < end) ? p : end - 1;
            int2 t2 = ep[q];
            if (p >= end) t2.y = 0;
            e[u] = t2;
        }
        __half2 v2[UN];
        __half v1[UN];
#pragma unroll
        for (int u = 0; u < UN; u++) {
            unsigned off = (unsigned)e[u].x;
            if (F == 64) off >>= 1;
            if (F == 128) v2[u] = *(const __half2*)((const char*)H + (off + lb));
            else          v1[u] = *(const __half*)((const char*)H + (off + lb));
        }
#pragma unroll
        for (int u = 0; u < UN; u++) {
            float w = __int_as_float(e[u].y);
            if (F == 128) {
                float2 f = __half22float2(v2[u]);
                a0 += w * f.x; a1 += w * f.y;
            } else {
                a0 += w * __half2float(v1[u]);
            }
        }
    }

    if (F == 128) {
        float o0 = a0 + bias[lane * 2];
        float o1 = a1 + bias[lane * 2 + 1];
        if (RELU) { o0 = fmaxf(o0, 0.f); o1 = fmaxf(o1, 0.f); }
        if (OF16) {
            ((__half2*)outv)[(size_t)node * 64 + lane] = __floats2half2_rn(o0, o1);
        } else {
            *(float2*)((float*)outv + (size_t)node * 128 + lane * 2) = make_float2(o0, o1);
        }
    } else {
        float o = a0 + bias[lane];
        if (RELU) o = fmaxf(o, 0.f);
        if (OF16) ((__half*)outv)[(size_t)node * 64 + lane] = __float2half(o);
        else      ((float*)outv)[(size_t)node * 64 + lane] = o;
    }
}

// ---------- launch ----------

extern "C" void kernel_launch(void* const* d_in, const int* in_sizes, int n_in,
                              void* d_out, int out_size, void* d_ws, size_t ws_size,
                              hipStream_t stream) {
    const float* x   = (const float*)d_in[0];
    const int*   ei  = (const int*)d_in[1];   // int32 (JAX x64 disabled)
    const float* ew  = (const float*)d_in[2];
    const float* W1  = (const float*)d_in[3];
    const float* b1  = (const float*)d_in[4];
    const float* W2  = (const float*)d_in[5];
    const float* b2  = (const float*)d_in[6];
    const float* W3  = (const float*)d_in[7];
    const float* b3  = (const float*)d_in[8];
    float* out = (float*)d_out;

    const int N = in_sizes[0] / K_IN;
    const int E = in_sizes[2];
    const int* src = ei;
    const int* dst = ei + E;

    const int NB   = (N + 255) >> 8;     // buckets, <=256
    const int NBLK = (E + CE - 1) / CE;  // partition blocks
    const int M    = NB * NBLK;
    const int NBB  = (M + 255) / 256;

    char* w = (char*)d_ws;
    auto alloc = [&](size_t bytes) {
        void* p = (void*)w;
        w += (bytes + 255) & ~(size_t)255;
        return p;
    };
    int*            counts = (int*)alloc((size_t)M * 4);
    int*            base   = (int*)alloc((size_t)M * 4);
    int*            bsM    = (int*)alloc((size_t)NBB * 4);
    int*            boM    = (int*)alloc((size_t)NBB * 4);
    unsigned short* lrank  = (unsigned short*)alloc((size_t)E * 2);  // reused as rank2
    int2*           arr1   = (int2*)alloc((size_t)E * 8);
    unsigned char*  dlow   = (unsigned char*)alloc((size_t)E);
    float*          dinv   = (float*)alloc((size_t)N * 4);
    int*            row_ptr= (int*)alloc((size_t)(N + 1) * 4);
    int2*           ep     = (int2*)alloc((size_t)E * 8);
    _Float16*       Wt1    = (_Float16*)alloc(128 * 128 * 2);
    _Float16*       Wt2    = (_Float16*)alloc(128 * 128 * 2);
    _Float16*       Wt3    = (_Float16*)alloc(64 * 128 * 2);
    _Float16*       bufH   = (_Float16*)alloc((size_t)N * 128 * 2);  // gemm out
    _Float16*       bufX   = (_Float16*)alloc((size_t)N * 128 * 2);  // agg out (fp16)

    // ---- CSR build (no global atomics) ----
    part_count<<<NBLK, 1024, 0, stream>>>(dst, counts, lrank, NB, NBLK, E);
    reduce_kernel<<<NBB, 256, 0, stream>>>(counts, bsM, M);
    scanb1024<<<1, 1024, 0, stream>>>(bsM, boM, NBB);
    scanw_kernel<<<NBB, 256, 0, stream>>>(counts, boM, base, M);
    part_scatter<<<NBLK, 1024, 0, stream>>>(src, dst, ew, base, lrank, arr1, dlow, NBLK, E);
    bucket_csr<<<NB, 1024, 0, stream>>>(arr1, dlow, base, lrank, dinv, row_ptr, ep,
                                        NB, NBLK, N, E);
    val_kernel<<<(E + 255) / 256, 256, 0, stream>>>(ep, dinv, row_ptr, N, E);

    // ---- W prep (fp16 transposed, single launch) ----
    wt_prep_all<<<(2 * 128 * 128 + 64 * 128 + 255) / 256, 256, 0, stream>>>(
        W1, W2, W3, Wt1, Wt2, Wt3);

    // ---- layers ----
    int gGemm = (N + 63) / 64;
    int gAgg  = (N + 3) / 4;

    mfma_gemm<128, false><<<gGemm, 256, 0, stream>>>(x, Wt1, bufH, N);
    agg_kernel<128, true, true><<<gAgg, 256, 0, stream>>>((const __half*)bufH, row_ptr, ep,
                                                          dinv, b1, bufX, N);
    mfma_gemm<128, true><<<gGemm, 256, 0, stream>>>(bufX, Wt2, bufH, N);
    agg_kernel<128, true, true><<<gAgg, 256, 0, stream>>>((const __half*)bufH, row_ptr, ep,
                                                          dinv, b2, bufX, N);
    mfma_gemm<64, true><<<gGemm, 256, 0, stream>>>(bufX, Wt3, bufH, N);
    agg_kernel<64, false, false><<<gAgg, 256, 0, stream>>>((const __half*)bufH, row_ptr, ep,
                                                           dinv, b3, out, N);
}

// Round 10
// 311.360 us; speedup vs baseline: 3.4241x; 1.0169x over previous
//
#include <hip/hip_runtime.h>
#include <hip/hip_bf16.h>
#include <hip/hip_fp16.h>

// GCN 3-layer. R10: (1) agg UN 16->24 (VGPR 24 had headroom; more gathers in
// flight). (2) part_scatter packs dlow into arr1.x (src<<8|dlow) -> one 8B
// scatter/edge, no dlow array. (3) bucket_csr: one packed 64-bit LDS atomic
// (cnt lo32 | fx hi32) instead of two 32-bit. (4) wt_prep fused into
// part_count tail blocks; val_kernel fused into gemm1 tail blocks ->
// 16->12 dispatches. R9's scalarized agg + MFMA gemms otherwise unchanged.

#define K_IN 128              // all layers have in_features == 128
#define FIX_SCALE 8388608.0f  // 2^23 fixed point for ew sums
#define CE 4096               // edges per partition block (1024 thr x 4)

typedef _Float16 f16x8 __attribute__((ext_vector_type(8)));
typedef float f32x4 __attribute__((ext_vector_type(4)));

// ---------- pass 1: per-block bucket histogram + local rank (+W prep tail) ----------
__global__ __launch_bounds__(1024) void part_count_wt(
    const int* __restrict__ dst, int* __restrict__ counts,
    unsigned short* __restrict__ lrank, int nb, int nblk, int e,
    const float* __restrict__ W1, const float* __restrict__ W2,
    const float* __restrict__ W3, _Float16* __restrict__ Wt1,
    _Float16* __restrict__ Wt2, _Float16* __restrict__ Wt3) {
    int blk = blockIdx.x;
    if (blk >= nblk) {  // tail blocks: Wt[n][k] fp16 = W[k][n] fp32
        int i = (blk - nblk) * 1024 + threadIdx.x;
        if (i < 128 * 128) {
            int k = i >> 7, nn = i & 127;
            Wt1[(size_t)nn * 128 + k] = (_Float16)W1[i];
        } else if (i < 2 * 128 * 128) {
            int j = i - 128 * 128, k = j >> 7, nn = j & 127;
            Wt2[(size_t)nn * 128 + k] = (_Float16)W2[j];
        } else if (i < 2 * 128 * 128 + 64 * 128) {
            int l = i - 2 * 128 * 128, k = l >> 6, nn = l & 63;
            Wt3[(size_t)nn * 128 + k] = (_Float16)W3[l];
        }
        return;
    }
    __shared__ int c[256];  // nb <= 256
    int t = threadIdx.x;
    for (int i = t; i < nb; i += 1024) c[i] = 0;
    __syncthreads();
    int b0 = blk * CE;
#pragma unroll
    for (int j = 0; j < 4; j++) {
        int i = b0 + j * 1024 + t;
        if (i < e) {
            int b = dst[i] >> 8;
            int r = atomicAdd(&c[b], 1);  // LDS atomic
            lrank[i] = (unsigned short)r;
        }
    }
    __syncthreads();
    for (int i = t; i < nb; i += 1024) counts[(size_t)i * nblk + blk] = c[i];
}

// ---------- pass 2: parallel exclusive scan over counts[nb*nblk] ----------
__global__ __launch_bounds__(256) void reduce_kernel(const int* __restrict__ v,
                                                     int* __restrict__ bs, int m) {
    __shared__ int s[256];
    int t = threadIdx.x, i = blockIdx.x * 256 + t;
    s[t] = (i < m) ? v[i] : 0;
    __syncthreads();
    for (int off = 128; off > 0; off >>= 1) {
        if (t < off) s[t] += s[t + off];
        __syncthreads();
    }
    if (t == 0) bs[blockIdx.x] = s[0];
}

__global__ __launch_bounds__(1024) void scanb1024(const int* __restrict__ bs,
                                                  int* __restrict__ bo, int nbb) {
    __shared__ int s[1024];
    int t = threadIdx.x;
    s[t] = (t < nbb) ? bs[t] : 0;
    __syncthreads();
    for (int off = 1; off < 1024; off <<= 1) {
        int cur = s[t];
        int add = (t >= off) ? s[t - off] : 0;
        __syncthreads();
        s[t] = cur + add;
        __syncthreads();
    }
    if (t < nbb) bo[t] = (t == 0) ? 0 : s[t - 1];
}

__global__ __launch_bounds__(256) void scanw_kernel(const int* __restrict__ v,
                                                    const int* __restrict__ bo,
                                                    int* __restrict__ outp, int m) {
    __shared__ int s[256];
    int t = threadIdx.x, i = blockIdx.x * 256 + t;
    int c = (i < m) ? v[i] : 0;
    s[t] = c;
    __syncthreads();
    for (int off = 1; off < 256; off <<= 1) {
        int cur = s[t];
        int add = (t >= off) ? s[t - off] : 0;
        __syncthreads();
        s[t] = cur + add;
        __syncthreads();
    }
    if (i < m) outp[i] = bo[blockIdx.x] + (s[t] - c);  // exclusive
}

// ---------- pass 3: scatter into bucket-sorted order (packed src|dlow) ----------
__global__ __launch_bounds__(1024) void part_scatter(const int* __restrict__ src,
                                                     const int* __restrict__ dst,
                                                     const float* __restrict__ ew,
                                                     const int* __restrict__ base,
                                                     const unsigned short* __restrict__ lrank,
                                                     int2* __restrict__ arr1,
                                                     int nblk, int e) {
    int t = threadIdx.x, blk = blockIdx.x;
    int b0 = blk * CE;
#pragma unroll
    for (int j = 0; j < 4; j++) {
        int i = b0 + j * 1024 + t;
        if (i < e) {
            int d = dst[i];
            int b = d >> 8;
            int pos = base[(size_t)b * nblk + blk] + lrank[i];
            arr1[pos] = make_int2((src[i] << 8) | (d & 255), __float_as_int(ew[i]));
        }
    }
}

// ---------- pass 4: per-bucket CSR finalize (one 64-bit LDS atomic/edge) ----------
__global__ __launch_bounds__(1024) void bucket_csr(const int2* __restrict__ arr1,
                                                   const int* __restrict__ base,
                                                   unsigned short* __restrict__ rank2,
                                                   float* __restrict__ dinv,
                                                   int* __restrict__ row_ptr,
                                                   int2* __restrict__ ep,
                                                   int nb, int nblk, int n, int e) {
    __shared__ unsigned long long pk[256];  // cnt lo32 | fx-sum hi32
    __shared__ int nbase[256];
    __shared__ float ldsdinv[256];
    __shared__ int ss[256];
    int t = threadIdx.x, b = blockIdx.x;
    int beg = base[(size_t)b * nblk];
    int end = (b + 1 < nb) ? base[(size_t)(b + 1) * nblk] : e;
    if (t < 256) pk[t] = 0ULL;
    __syncthreads();
    for (int i = beg + t; i < end; i += 1024) {
        int2 a = arr1[i];
        int ld = a.x & 255;
        float w = __int_as_float(a.y);
        unsigned long long fx = (unsigned long long)(unsigned int)(w * FIX_SCALE + 0.5f);
        unsigned long long old = atomicAdd(&pk[ld], (fx << 32) | 1ULL);  // LDS, deterministic
        rank2[i] = (unsigned short)(old & 0xffffffffULL);
    }
    __syncthreads();
    int cnt = (t < 256) ? (int)(pk[t] & 0xffffffffULL) : 0;
    if (t < 256) ss[t] = cnt;
    __syncthreads();
    for (int off = 1; off < 256; off <<= 1) {
        int cur = 0, add = 0;
        if (t < 256) { cur = ss[t]; add = (t >= off) ? ss[t - off] : 0; }
        __syncthreads();
        if (t < 256) ss[t] = cur + add;
        __syncthreads();
    }
    if (t < 256) {
        nbase[t] = ss[t] - cnt;
        int d = b * 256 + t;
        if (d < n) {
            float dv = rsqrtf(1.0f + (float)(unsigned int)(pk[t] >> 32) * (1.0f / FIX_SCALE));
            dinv[d] = dv;
            ldsdinv[t] = dv;
            row_ptr[d] = beg + nbase[t];
        }
    }
    __syncthreads();
    for (int i = beg + t; i < end; i += 1024) {
        int2 a = arr1[i];
        int ld = a.x & 255;
        int pos = beg + nbase[ld] + rank2[i];
        float w = __int_as_float(a.y) * ldsdinv[ld];
        ep[pos] = make_int2(a.x >> 8, __float_as_int(w));  // src index, w*dinv[dst]
    }
}

// ---------- MFMA GEMM (+optional fused val pass in tail blocks) ----------
// H[n x NOUT](fp16) = X[n x 128] @ W. val: ep -> (src*256 byte off, w*dinv[src]).
template <int NOUT, bool XF16, bool FUSEVAL>
__global__ __launch_bounds__(256) void mfma_gemm(const void* __restrict__ Xv,
                                                 const _Float16* __restrict__ Wt,
                                                 _Float16* __restrict__ H, int n,
                                                 int gGemm, int vblk,
                                                 int2* __restrict__ ep,
                                                 const float* __restrict__ dinv,
                                                 int* __restrict__ row_ptr, int e) {
    constexpr int CTW = NOUT / 64;  // col-tiles per wave: 2 (NOUT=128) / 1 (64)
    __shared__ _Float16 Xs[64][136];   // +8 pad: row stride 272B -> 2-way banks
    __shared__ _Float16 Ws[NOUT][136];
    int t = threadIdx.x;
    if (FUSEVAL && (int)blockIdx.x >= gGemm) {  // tail blocks: val pass
        int vb = blockIdx.x - gGemm;
        if (vb == 0 && t == 0) row_ptr[n] = e;
        for (int i = vb * 256 + t; i < e; i += vblk * 256) {
            int2 a = ep[i];
            float w = __int_as_float(a.y) * dinv[a.x];
            ep[i] = make_int2(a.x << 8, __float_as_int(w));  // byte off (fp16 row F=128)
        }
        return;
    }
    int row0 = blockIdx.x * 64;

    for (int i = t * 8; i < NOUT * K_IN; i += 2048) {
        int nn = i >> 7, k = i & 127;
        *(uint4*)&Ws[nn][k] = *(const uint4*)&Wt[i];
    }
    if (XF16) {
        const _Float16* X = (const _Float16*)Xv;
        for (int i = t * 8; i < 64 * K_IN; i += 2048) {
            int r = i >> 7, k = i & 127;
            int row = row0 + r;
            uint4 v = make_uint4(0u, 0u, 0u, 0u);
            if (row < n) v = *(const uint4*)(X + (size_t)row * K_IN + k);
            *(uint4*)&Xs[r][k] = v;
        }
    } else {
        const float* X = (const float*)Xv;
        for (int i = t * 4; i < 64 * K_IN; i += 1024) {
            int r = i >> 7, k = i & 127;
            int row = row0 + r;
            float4 x4 = make_float4(0.f, 0.f, 0.f, 0.f);
            if (row < n) x4 = *(const float4*)(X + (size_t)row * K_IN + k);
            union { _Float16 h[4]; uint2 u; } uu;
            uu.h[0] = (_Float16)x4.x; uu.h[1] = (_Float16)x4.y;
            uu.h[2] = (_Float16)x4.z; uu.h[3] = (_Float16)x4.w;
            *(uint2*)&Xs[r][k] = uu.u;
        }
    }
    __syncthreads();

    int lane = t & 63, w = t >> 6;
    int m = lane & 15, g = lane >> 4;
    f32x4 acc[4][CTW];
#pragma unroll
    for (int mt = 0; mt < 4; mt++)
#pragma unroll
        for (int ct = 0; ct < CTW; ct++) acc[mt][ct] = (f32x4){0.f, 0.f, 0.f, 0.f};

#pragma unroll
    for (int kt = 0; kt < 4; kt++) {
        int kb = kt * 32 + g * 8;
        f16x8 a[4];
#pragma unroll
        for (int mt = 0; mt < 4; mt++) a[mt] = *(const f16x8*)&Xs[mt * 16 + m][kb];
#pragma unroll
        for (int ct = 0; ct < CTW; ct++) {
            int nn = w * (16 * CTW) + ct * 16 + m;
            f16x8 b = *(const f16x8*)&Ws[nn][kb];
#pragma unroll
            for (int mt = 0; mt < 4; mt++)
                acc[mt][ct] = __builtin_amdgcn_mfma_f32_16x16x32_f16(a[mt], b, acc[mt][ct], 0, 0, 0);
        }
    }

#pragma unroll
    for (int mt = 0; mt < 4; mt++) {
#pragma unroll
        for (int r = 0; r < 4; r++) {
            int row = row0 + mt * 16 + g * 4 + r;
            if (row < n) {
#pragma unroll
                for (int ct = 0; ct < CTW; ct++)
                    H[(size_t)row * NOUT + w * (16 * CTW) + ct * 16 + m] =
                        (_Float16)acc[mt][ct][r];
            }
        }
    }
}

// ---------- aggregation: scalar ep loads, 1-VALU-add gathers, fp32 accum ----------
template <int F, bool RELU, bool OF16>
__global__ __launch_bounds__(256) void agg_kernel(const __half* __restrict__ H,
                                                  const int* __restrict__ row_ptr,
                                                  const int2* __restrict__ ep,
                                                  const float* __restrict__ dinv,
                                                  const float* __restrict__ bias,
                                                  void* __restrict__ outv, int n) {
    constexpr int UN = 24;
    int wid = threadIdx.x >> 6;
    int lane = threadIdx.x & 63;
    int node = blockIdx.x * 4 + wid;
    if (node >= n) return;

    int start = __builtin_amdgcn_readfirstlane(row_ptr[node]);
    int end   = __builtin_amdgcn_readfirstlane(row_ptr[node + 1]);
    float di = dinv[node];
    float sw = di * di;

    const unsigned lb = (unsigned)lane * (F == 128 ? 4u : 2u);  // lane byte offset

    float a0, a1;
    if (F == 128) {
        float2 s2 = __half22float2(((const __half2*)(H + (size_t)node * 128))[lane]);
        a0 = s2.x * sw; a1 = s2.y * sw;
    } else {
        a0 = __half2float(H[(size_t)node * 64 + lane]) * sw; a1 = 0.f;
    }

    int len = end - start;
    int nf = len / UN;
    for (int b = 0; b < nf; b++) {
        int p0 = start + b * UN;
        int2 e[UN];
#pragma unroll
        for (int u = 0; u < UN; u++) e[u] = ep[p0 + u];  // uniform addr -> s_load
        __half2 v2[UN];
        __half v1[UN];
#pragma unroll
        for (int u = 0; u < UN; u++) {
            unsigned off = (unsigned)e[u].x;
            if (F == 64) off >>= 1;
            if (F == 128) v2[u] = *(const __half2*)((const char*)H + (off + lb));
            else          v1[u] = *(const __half*)((const char*)H + (off + lb));
        }
#pragma unroll
        for (int u = 0; u < UN; u++) {
            float w = __int_as_float(e[u].y);
            if (F == 128) {
                float2 f = __half22float2(v2[u]);
                a0 += w * f.x; a1 += w * f.y;
            } else {
                a0 += w * __half2float(v1[u]);
            }
        }
    }
    int base = start + nf * UN;
    if (base < end) {  // single predicated tail batch (uniform predicates)
        int2 e[UN];
#pragma unroll
        for (int u = 0; u < UN; u++) {
            int p = base + u;
            int q = (p < end) ? p : end - 1;
            int2 t2 = ep[q];
            if (p >= end) t2.y = 0;
            e[u] = t2;
        }
        __half2 v2[UN];
        __half v1[UN];
#pragma unroll
        for (int u = 0; u < UN; u++) {
            unsigned off = (unsigned)e[u].x;
            if (F == 64) off >>= 1;
            if (F == 128) v2[u] = *(const __half2*)((const char*)H + (off + lb));
            else          v1[u] = *(const __half*)((const char*)H + (off + lb));
        }
#pragma unroll
        for (int u = 0; u < UN; u++) {
            float w = __int_as_float(e[u].y);
            if (F == 128) {
                float2 f = __half22float2(v2[u]);
                a0 += w * f.x; a1 += w * f.y;
            } else {
                a0 += w * __half2float(v1[u]);
            }
        }
    }

    if (F == 128) {
        float o0 = a0 + bias[lane * 2];
        float o1 = a1 + bias[lane * 2 + 1];
        if (RELU) { o0 = fmaxf(o0, 0.f); o1 = fmaxf(o1, 0.f); }
        if (OF16) {
            ((__half2*)outv)[(size_t)node * 64 + lane] = __floats2half2_rn(o0, o1);
        } else {
            *(float2*)((float*)outv + (size_t)node * 128 + lane * 2) = make_float2(o0, o1);
        }
    } else {
        float o = a0 + bias[lane];
        if (RELU) o = fmaxf(o, 0.f);
        if (OF16) ((__half*)outv)[(size_t)node * 64 + lane] = __float2half(o);
        else      ((float*)outv)[(size_t)node * 64 + lane] = o;
    }
}

// ---------- launch ----------

extern "C" void kernel_launch(void* const* d_in, const int* in_sizes, int n_in,
                              void* d_out, int out_size, void* d_ws, size_t ws_size,
                              hipStream_t stream) {
    const float* x   = (const float*)d_in[0];
    const int*   ei  = (const int*)d_in[1];   // int32 (JAX x64 disabled)
    const float* ew  = (const float*)d_in[2];
    const float* W1  = (const float*)d_in[3];
    const float* b1  = (const float*)d_in[4];
    const float* W2  = (const float*)d_in[5];
    const float* b2  = (const float*)d_in[6];
    const float* W3  = (const float*)d_in[7];
    const float* b3  = (const float*)d_in[8];
    float* out = (float*)d_out;

    const int N = in_sizes[0] / K_IN;
    const int E = in_sizes[2];
    const int* src = ei;
    const int* dst = ei + E;

    const int NB   = (N + 255) >> 8;     // buckets, <=256
    const int NBLK = (E + CE - 1) / CE;  // partition blocks
    const int M    = NB * NBLK;
    const int NBB  = (M + 255) / 256;
    const int NWT  = (2 * 128 * 128 + 64 * 128 + 1023) / 1024;  // wt_prep tail blocks
    const int VBLK = 1024;                                      // val tail blocks

    char* w = (char*)d_ws;
    auto alloc = [&](size_t bytes) {
        void* p = (void*)w;
        w += (bytes + 255) & ~(size_t)255;
        return p;
    };
    int*            counts = (int*)alloc((size_t)M * 4);
    int*            base   = (int*)alloc((size_t)M * 4);
    int*            bsM    = (int*)alloc((size_t)NBB * 4);
    int*            boM    = (int*)alloc((size_t)NBB * 4);
    unsigned short* lrank  = (unsigned short*)alloc((size_t)E * 2);  // reused as rank2
    int2*           arr1   = (int2*)alloc((size_t)E * 8);
    float*          dinv   = (float*)alloc((size_t)N * 4);
    int*            row_ptr= (int*)alloc((size_t)(N + 1) * 4);
    int2*           ep     = (int2*)alloc((size_t)E * 8);
    _Float16*       Wt1    = (_Float16*)alloc(128 * 128 * 2);
    _Float16*       Wt2    = (_Float16*)alloc(128 * 128 * 2);
    _Float16*       Wt3    = (_Float16*)alloc(64 * 128 * 2);
    _Float16*       bufH   = (_Float16*)alloc((size_t)N * 128 * 2);  // gemm out
    _Float16*       bufX   = (_Float16*)alloc((size_t)N * 128 * 2);  // agg out (fp16)

    int gGemm = (N + 63) / 64;
    int gAgg  = (N + 3) / 4;

    // ---- CSR build (no global atomics) + fused W prep ----
    part_count_wt<<<NBLK + NWT, 1024, 0, stream>>>(dst, counts, lrank, NB, NBLK, E,
                                                   W1, W2, W3, Wt1, Wt2, Wt3);
    reduce_kernel<<<NBB, 256, 0, stream>>>(counts, bsM, M);
    scanb1024<<<1, 1024, 0, stream>>>(bsM, boM, NBB);
    scanw_kernel<<<NBB, 256, 0, stream>>>(counts, boM, base, M);
    part_scatter<<<NBLK, 1024, 0, stream>>>(src, dst, ew, base, lrank, arr1, NBLK, E);
    bucket_csr<<<NB, 1024, 0, stream>>>(arr1, base, lrank, dinv, row_ptr, ep,
                                        NB, NBLK, N, E);

    // ---- layers (gemm1 carries the fused val pass in tail blocks) ----
    mfma_gemm<128, false, true><<<gGemm + VBLK, 256, 0, stream>>>(
        x, Wt1, bufH, N, gGemm, VBLK, ep, dinv, row_ptr, E);
    agg_kernel<128, true, true><<<gAgg, 256, 0, stream>>>((const __half*)bufH, row_ptr, ep,
                                                          dinv, b1, bufX, N);
    mfma_gemm<128, true, false><<<gGemm, 256, 0, stream>>>(
        bufX, Wt2, bufH, N, gGemm, 0, nullptr, nullptr, nullptr, 0);
    agg_kernel<128, true, true><<<gAgg, 256, 0, stream>>>((const __half*)bufH, row_ptr, ep,
                                                          dinv, b2, bufX, N);
    mfma_gemm<64, true, false><<<gGemm, 256, 0, stream>>>(
        bufX, Wt3, bufH, N, gGemm, 0, nullptr, nullptr, nullptr, 0);
    agg_kernel<64, false, false><<<gAgg, 256, 0, stream>>>((const __half*)bufH, row_ptr, ep,
                                                           dinv, b3, out, N);
}